// Round 1
// baseline (1546.255 us; speedup 1.0000x reference)
//
#include <hip/hip_runtime.h>
#include <math.h>

#define NB   8
#define CIN  128
#define CC   256
#define GG   8
#define CGR  32      // channels per group
#define HH   36
#define WW   36
#define HWP  1296    // H*W
#define DH   34
#define DW   34
#define DD   1156    // DH*DW

#define TQ   16      // q rows per attention block
#define TD   64      // d tile
#define NDT  ((DD + TD - 1) / TD)   // 19

// ---------------- 1x1 projection: x = W_xi * x_in ----------------
__global__ __launch_bounds__(256) void k_proj(const float* __restrict__ x_in,
                                              const float* __restrict__ W_xi,
                                              float* __restrict__ x) {
    int co = blockIdx.x, n = blockIdx.y;
    const float* w  = W_xi + co * CIN;
    const float* xb = x_in + (size_t)n * CIN * HWP;
    float* xo = x + ((size_t)n * CC + co) * HWP;
    for (int p4 = threadIdx.x; p4 < HWP / 4; p4 += 256) {
        float4 s = {0.f, 0.f, 0.f, 0.f};
        for (int ci = 0; ci < CIN; ci++) {
            float4 xv = *(const float4*)(xb + ci * HWP + p4 * 4);
            float wv = w[ci];
            s.x += wv * xv.x; s.y += wv * xv.y; s.z += wv * xv.z; s.w += wv * xv.w;
        }
        *(float4*)(xo + p4 * 4) = s;
    }
}

// ---------------- q conv: grouped 3x3 SAME on (x interleaved with zero h) ----------------
// Only first CGR input channels of each group's 2*CGR are nonzero.
__global__ __launch_bounds__(256) void k_qconv(const float* __restrict__ x,
                                               const float* __restrict__ Wq,
                                               float* __restrict__ q) {
    int oc = blockIdx.x, n = blockIdx.y;
    int g = oc >> 5;
    const float* xg = x + ((size_t)n * CC + g * CGR) * HWP;
    const float* w  = Wq + (size_t)oc * (2 * CGR * 9);
    float* qo = q + ((size_t)n * CC + oc) * HWP;
    for (int p = threadIdx.x; p < HWP; p += 256) {
        int y = p / WW, xx = p % WW;
        float s = 0.f;
        for (int ci = 0; ci < CGR; ci++) {
            const float* xc = xg + ci * HWP;
            const float* wc = w + ci * 9;
            #pragma unroll
            for (int ky = 0; ky < 3; ky++) {
                int iy = y + ky - 1;
                if ((unsigned)iy >= HH) continue;
                #pragma unroll
                for (int kx = 0; kx < 3; kx++) {
                    int ix = xx + kx - 1;
                    if ((unsigned)ix >= WW) continue;
                    s += wc[ky * 3 + kx] * xc[iy * WW + ix];
                }
            }
        }
        qo[p] = s;
    }
}

// ---------------- k,v conv: grouped 3x3 VALID (fused, shares x loads) ----------------
__global__ __launch_bounds__(256) void k_kvconv(const float* __restrict__ x,
                                                const float* __restrict__ Wk,
                                                const float* __restrict__ Wv,
                                                float* __restrict__ kk,
                                                float* __restrict__ vv) {
    int oc = blockIdx.x, n = blockIdx.y;
    int g = oc >> 5;
    const float* xg = x + ((size_t)n * CC + g * CGR) * HWP;
    const float* wk = Wk + (size_t)oc * (2 * CGR * 9);
    const float* wv = Wv + (size_t)oc * (2 * CGR * 9);
    float* ko = kk + ((size_t)n * CC + oc) * DD;
    float* vo = vv + ((size_t)n * CC + oc) * DD;
    for (int d = threadIdx.x; d < DD; d += 256) {
        int y = d / DW, xx = d % DW;
        float sk = 0.f, sv = 0.f;
        for (int ci = 0; ci < CGR; ci++) {
            const float* xc = xg + ci * HWP + y * WW + xx;
            const float* wkc = wk + ci * 9;
            const float* wvc = wv + ci * 9;
            #pragma unroll
            for (int ky = 0; ky < 3; ky++) {
                #pragma unroll
                for (int kx = 0; kx < 3; kx++) {
                    float xv = xc[ky * WW + kx];
                    sk += wkc[ky * 3 + kx] * xv;
                    sv += wvc[ky * 3 + kx] * xv;
                }
            }
        }
        ko[d] = sk;
        vo[d] = sv;
    }
}

// ---------------- fused attention: softmax_d(tau * q^T k) @ v^T ----------------
__global__ __launch_bounds__(256) void k_attn(const float* __restrict__ q,
                                              const float* __restrict__ kk,
                                              const float* __restrict__ vv,
                                              const float* __restrict__ tau,
                                              float* __restrict__ a) {
    int qt = blockIdx.x;     // 0..80
    int g  = blockIdx.y;
    int n  = blockIdx.z;
    int q0 = qt * TQ;
    int tid = threadIdx.x;

    __shared__ float q_s[TQ][CGR];
    __shared__ float k_s[CGR][TD + 4];
    __shared__ float v_s[CGR][TD + 4];
    __shared__ float w_s[TQ][TD + 4];
    __shared__ float m_s[TQ], s_s[TQ], sc_s[TQ];

    const float taug = tau[g];
    const float* qg = q  + ((size_t)n * CC + g * CGR) * HWP;
    const float* kg = kk + ((size_t)n * CC + g * CGR) * DD;
    const float* vg = vv + ((size_t)n * CC + g * CGR) * DD;

    for (int idx = tid; idx < TQ * CGR; idx += 256) {
        int c = idx >> 4, r = idx & 15;
        q_s[r][c] = qg[c * HWP + q0 + r];
    }
    if (tid < TQ) { m_s[tid] = -1e30f; s_s[tid] = 0.f; }
    __syncthreads();

    // QK mapping: row rA (0..15), 16 cols of 4 d's
    int rA = tid >> 4, jA = tid & 15;
    // PV mapping: channel cB (0..31), 8 cols of 8 d's
    int cB = tid >> 3, jB = tid & 7;

    float acc[TQ];
    #pragma unroll
    for (int r = 0; r < TQ; r++) acc[r] = 0.f;

    for (int dt = 0; dt < NDT; dt++) {
        int d0 = dt * TD;
        for (int idx = tid; idx < CGR * TD; idx += 256) {
            int c = idx / TD, dl = idx % TD;
            int d = d0 + dl;
            float kvK = 0.f, kvV = 0.f;
            if (d < DD) { kvK = kg[c * DD + d]; kvV = vg[c * DD + d]; }
            k_s[c][dl] = kvK;
            v_s[c][dl] = kvV;
        }
        __syncthreads();

        // ---- QK: 4 logits per thread ----
        float l0 = 0.f, l1 = 0.f, l2 = 0.f, l3 = 0.f;
        #pragma unroll 8
        for (int c = 0; c < CGR; c++) {
            float qc = q_s[rA][c];
            float4 kv = *(const float4*)&k_s[c][jA * 4];
            l0 += qc * kv.x; l1 += qc * kv.y; l2 += qc * kv.z; l3 += qc * kv.w;
        }
        l0 *= taug; l1 *= taug; l2 *= taug; l3 *= taug;
        int dbase = d0 + jA * 4;
        if (dbase + 0 >= DD) l0 = -1e30f;
        if (dbase + 1 >= DD) l1 = -1e30f;
        if (dbase + 2 >= DD) l2 = -1e30f;
        if (dbase + 3 >= DD) l3 = -1e30f;

        float mx = fmaxf(fmaxf(l0, l1), fmaxf(l2, l3));
        #pragma unroll
        for (int o = 1; o < 16; o <<= 1) mx = fmaxf(mx, __shfl_xor(mx, o));
        float mold = m_s[rA];
        float mnew = fmaxf(mold, mx);
        float e0 = expf(l0 - mnew), e1 = expf(l1 - mnew);
        float e2 = expf(l2 - mnew), e3 = expf(l3 - mnew);
        float rs = e0 + e1 + e2 + e3;
        #pragma unroll
        for (int o = 1; o < 16; o <<= 1) rs += __shfl_xor(rs, o);
        w_s[rA][jA * 4 + 0] = e0;
        w_s[rA][jA * 4 + 1] = e1;
        w_s[rA][jA * 4 + 2] = e2;
        w_s[rA][jA * 4 + 3] = e3;
        if (jA == 0) {
            float scale = expf(mold - mnew);
            s_s[rA] = s_s[rA] * scale + rs;
            m_s[rA] = mnew;
            sc_s[rA] = scale;
        }
        __syncthreads();

        // ---- PV: each thread owns (cB, 8 d's), accumulates all 16 rows ----
        float4 va = *(const float4*)&v_s[cB][jB * 8];
        float4 vb = *(const float4*)&v_s[cB][jB * 8 + 4];
        #pragma unroll
        for (int r = 0; r < TQ; r++) {
            float4 wa = *(const float4*)&w_s[r][jB * 8];
            float4 wb = *(const float4*)&w_s[r][jB * 8 + 4];
            float p = wa.x * va.x + wa.y * va.y + wa.z * va.z + wa.w * va.w
                    + wb.x * vb.x + wb.y * vb.y + wb.z * vb.z + wb.w * vb.w;
            acc[r] = acc[r] * sc_s[r] + p;
        }
        __syncthreads();
    }

    float* ag = a + ((size_t)n * CC + g * CGR + cB) * HWP + q0;
    #pragma unroll
    for (int r = 0; r < TQ; r++) {
        float t = acc[r];
        #pragma unroll
        for (int o = 1; o < 8; o <<= 1) t += __shfl_xor(t, o);
        if (jB == 0) ag[r] = t / s_s[r];
    }
}

// ---------------- gates (i, g, o only; f is dead since c=0) + LSTM math ----------------
__global__ __launch_bounds__(256) void k_gates(const float* __restrict__ x,
                                               const float* __restrict__ a,
                                               const float* __restrict__ Wi_a, const float* __restrict__ Wi_x,
                                               const float* __restrict__ b_i,  const float* __restrict__ g_i,
                                               const float* __restrict__ Wg_a, const float* __restrict__ Wg_x,
                                               const float* __restrict__ b_g,  const float* __restrict__ g_g,
                                               const float* __restrict__ Wo_a, const float* __restrict__ Wo_x,
                                               const float* __restrict__ b_o,  const float* __restrict__ g_o,
                                               float* __restrict__ out) {
    int oc = blockIdx.x, n = blockIdx.y;
    int g = oc >> 5;
    const float* xg = x + ((size_t)n * CC + g * CGR) * HWP;
    const float* ag = a + ((size_t)n * CC + g * CGR) * HWP;
    const float* wia = Wi_a + oc * CGR;
    const float* wga = Wg_a + oc * CGR;
    const float* woa = Wo_a + oc * CGR;
    const float* wix = Wi_x + (size_t)oc * (2 * CGR * 9);
    const float* wgx = Wg_x + (size_t)oc * (2 * CGR * 9);
    const float* wox = Wo_x + (size_t)oc * (2 * CGR * 9);
    float bi = b_i[oc], gi = g_i[oc];
    float bg = b_g[oc], gg = g_g[oc];
    float bo = b_o[oc], go = g_o[oc];
    float* oo = out + ((size_t)n * CC + oc) * HWP;

    for (int p = threadIdx.x; p < HWP; p += 256) {
        int y = p / WW, xx = p % WW;
        float zi = 0.f, zg = 0.f, zo = 0.f;
        for (int c = 0; c < CGR; c++) {
            float av = ag[c * HWP + p];
            zi += wia[c] * av;
            zg += wga[c] * av;
            zo += woa[c] * av;
        }
        for (int ci = 0; ci < CGR; ci++) {
            const float* xc = xg + ci * HWP;
            int wb = ci * 9;
            #pragma unroll
            for (int ky = 0; ky < 3; ky++) {
                int iy = y + ky - 1;
                if ((unsigned)iy >= HH) continue;
                #pragma unroll
                for (int kx = 0; kx < 3; kx++) {
                    int ix = xx + kx - 1;
                    if ((unsigned)ix >= WW) continue;
                    float xv = xc[iy * WW + ix];
                    int wi = wb + ky * 3 + kx;
                    zi += wix[wi] * xv;
                    zg += wgx[wi] * xv;
                    zo += wox[wi] * xv;
                }
            }
        }
        float iv = 1.f / (1.f + expf(-(gi * zi + bi)));
        float gv = tanhf(gg * zg + bg);
        float ov = 1.f / (1.f + expf(-(go * zo + bo)));
        oo[p] = ov * tanhf(iv * gv);
    }
}

extern "C" void kernel_launch(void* const* d_in, const int* in_sizes, int n_in,
                              void* d_out, int out_size, void* d_ws, size_t ws_size,
                              hipStream_t stream) {
    const float* x_in = (const float*)d_in[0];
    // d_in[1] = W_xh (dead: h = 0)
    const float* W_xi = (const float*)d_in[2];
    const float* Wq   = (const float*)d_in[3];
    const float* Wk   = (const float*)d_in[4];
    const float* Wv   = (const float*)d_in[5];
    const float* Wi_a = (const float*)d_in[6];
    const float* Wi_x = (const float*)d_in[7];
    const float* b_i  = (const float*)d_in[8];
    const float* g_i  = (const float*)d_in[9];
    // d_in[10..13] = Wf_a, Wf_x, b_f, g_f (dead: c = 0)
    const float* Wg_a = (const float*)d_in[14];
    const float* Wg_x = (const float*)d_in[15];
    const float* b_g  = (const float*)d_in[16];
    const float* g_g  = (const float*)d_in[17];
    const float* Wo_a = (const float*)d_in[18];
    const float* Wo_x = (const float*)d_in[19];
    const float* b_o  = (const float*)d_in[20];
    const float* g_o  = (const float*)d_in[21];
    const float* tau  = (const float*)d_in[22];
    float* out = (float*)d_out;

    float* ws = (float*)d_ws;
    const size_t sz_x = (size_t)NB * CC * HWP;   // 2654208
    const size_t sz_d = (size_t)NB * CC * DD;    // 2367488
    float* x  = ws;
    float* q  = x + sz_x;
    float* kk = q + sz_x;
    float* vv = kk + sz_d;
    float* aa = vv + sz_d;

    dim3 blk(256);
    k_proj<<<dim3(CC, NB), blk, 0, stream>>>(x_in, W_xi, x);
    k_qconv<<<dim3(CC, NB), blk, 0, stream>>>(x, Wq, q);
    k_kvconv<<<dim3(CC, NB), blk, 0, stream>>>(x, Wk, Wv, kk, vv);
    k_attn<<<dim3(HWP / TQ, GG, NB), blk, 0, stream>>>(q, kk, vv, tau, aa);
    k_gates<<<dim3(CC, NB), blk, 0, stream>>>(x, aa,
                                              Wi_a, Wi_x, b_i, g_i,
                                              Wg_a, Wg_x, b_g, g_g,
                                              Wo_a, Wo_x, b_o, g_o,
                                              out);
}

// Round 2
// 734.809 us; speedup vs baseline: 2.1043x; 2.1043x over previous
//
#include <hip/hip_runtime.h>
#include <math.h>

#define NB   8
#define CIN  128
#define CC   256
#define GG   8
#define CGR  32      // channels per group
#define HH   36
#define WW   36
#define HWP  1296    // H*W
#define DHH  34
#define DD   1156    // 34*34

#define TQ   16      // q rows per attention block
#define TD   64      // d tile
#define NDT  ((DD + TD - 1) / TD)   // 19

// ---------------- 1x1 projection: x = W_xi * x_in ----------------
// block: (oc-chunk of 64, row-tile of 2 rows, n). LDS-staged input, 18 px/thread.
__global__ __launch_bounds__(256) void k_proj(const float* __restrict__ x_in,
                                              const float* __restrict__ W_xi,
                                              float* __restrict__ x) {
    __shared__ float xs[CIN * 72];
    int chunk = blockIdx.x, rt = blockIdx.y, n = blockIdx.z;
    int p0 = rt * 72;
    const float* xb = x_in + (size_t)n * CIN * HWP + p0;
    for (int idx = threadIdx.x; idx < CIN * 72; idx += 256) {
        int ci = idx / 72, c = idx % 72;
        xs[idx] = xb[ci * HWP + c];
    }
    __syncthreads();
    int oc = chunk * 64 + (threadIdx.x >> 2);
    int j = threadIdx.x & 3;
    const float* w = W_xi + oc * CIN;
    const float* xsj = xs + j * 18;
    float acc[18];
    #pragma unroll
    for (int t = 0; t < 18; t++) acc[t] = 0.f;
    for (int ci = 0; ci < CIN; ci++) {
        float wv = w[ci];
        const float* xr = xsj + ci * 72;
        #pragma unroll
        for (int t = 0; t < 18; t++) acc[t] += wv * xr[t];
    }
    float* xo = x + ((size_t)n * CC + oc) * HWP + p0 + j * 18;
    #pragma unroll
    for (int t = 0; t < 18; t++) xo[t] = acc[t];
}

// ---------------- fused q/k/v grouped 3x3 conv ----------------
// q: SAME on padded tile. k,v: VALID — kv[y-1][x-1] uses the SAME taps as q[y][x],
// so one LDS read feeds 3 FMAs. block: (4-row tile, g, n); thread: (oc, 18-px run).
__global__ __launch_bounds__(256) void k_qkv(const float* __restrict__ x,
                                             const float* __restrict__ Wq,
                                             const float* __restrict__ Wk,
                                             const float* __restrict__ Wv,
                                             float* __restrict__ q,
                                             float* __restrict__ kk,
                                             float* __restrict__ vv) {
    __shared__ float xs[CGR][6][38];    // rows y0-1..y0+4, cols -1..36 (zero-padded)
    int rt = blockIdx.x, g = blockIdx.y, n = blockIdx.z;
    int y0 = rt * 4;
    const float* xg = x + ((size_t)n * CC + g * CGR) * HWP;
    for (int idx = threadIdx.x; idx < CGR * 6 * 38; idx += 256) {
        int ci = idx / (6 * 38);
        int rem = idx % (6 * 38);
        int r = rem / 38, c = rem % 38;
        int yy = y0 - 1 + r, cx = c - 1;
        float v = 0.f;
        if ((unsigned)yy < HH && (unsigned)cx < WW) v = xg[ci * HWP + yy * WW + cx];
        (&xs[0][0][0])[idx] = v;
    }
    __syncthreads();

    int oc = threadIdx.x >> 3;          // 0..31
    int j  = threadIdx.x & 7;
    int rq = j >> 1, cq = (j & 1) * 18; // q pixel (y0+rq, cq..cq+17)
    int ocg = g * CGR + oc;
    const float* wq = Wq + (size_t)ocg * 576;
    const float* wk = Wk + (size_t)ocg * 576;
    const float* wv = Wv + (size_t)ocg * 576;

    float qa[18], ka[18], va[18];
    #pragma unroll
    for (int t = 0; t < 18; t++) { qa[t] = 0.f; ka[t] = 0.f; va[t] = 0.f; }

    for (int ci = 0; ci < CGR; ci++) {
        #pragma unroll
        for (int ky = 0; ky < 3; ky++) {
            const float* xr = &xs[ci][rq + ky][cq];
            #pragma unroll
            for (int kx = 0; kx < 3; kx++) {
                int kidx = ci * 9 + ky * 3 + kx;
                float wqv = wq[kidx], wkv = wk[kidx], wvv = wv[kidx];
                #pragma unroll
                for (int t = 0; t < 18; t++) {
                    float xv = xr[kx + t];
                    qa[t] += wqv * xv;
                    ka[t] += wkv * xv;
                    va[t] += wvv * xv;
                }
            }
        }
    }

    float* qo = q + ((size_t)n * CC + ocg) * HWP + (y0 + rq) * WW + cq;
    #pragma unroll
    for (int t = 0; t < 18; t++) qo[t] = qa[t];

    int yd = y0 + rq - 1;               // kv output row = q row - 1
    if ((unsigned)yd < DHH) {
        float* ko = kk + ((size_t)n * CC + ocg) * DD + yd * DHH;
        float* vo = vv + ((size_t)n * CC + ocg) * DD + yd * DHH;
        #pragma unroll
        for (int t = 0; t < 18; t++) {
            int xd = cq + t - 1;        // kv output col = q col - 1
            if ((unsigned)xd < DHH) { ko[xd] = ka[t]; vo[xd] = va[t]; }
        }
    }
}

// ---------------- fused attention: softmax_d(tau * q^T k) @ v^T ----------------
__global__ __launch_bounds__(256) void k_attn(const float* __restrict__ q,
                                              const float* __restrict__ kk,
                                              const float* __restrict__ vv,
                                              const float* __restrict__ tau,
                                              float* __restrict__ a) {
    int qt = blockIdx.x;     // 0..80
    int g  = blockIdx.y;
    int n  = blockIdx.z;
    int q0 = qt * TQ;
    int tid = threadIdx.x;

    __shared__ float q_s[TQ][CGR];
    __shared__ float k_s[CGR][TD + 4];
    __shared__ float v_s[CGR][TD + 4];
    __shared__ float w_s[TQ][TD + 4];
    __shared__ float m_s[TQ], s_s[TQ], sc_s[TQ];

    const float taug = tau[g];
    const float* qg = q  + ((size_t)n * CC + g * CGR) * HWP;
    const float* kg = kk + ((size_t)n * CC + g * CGR) * DD;
    const float* vg = vv + ((size_t)n * CC + g * CGR) * DD;

    for (int idx = tid; idx < TQ * CGR; idx += 256) {
        int c = idx >> 4, r = idx & 15;
        q_s[r][c] = qg[c * HWP + q0 + r];
    }
    if (tid < TQ) { m_s[tid] = -1e30f; s_s[tid] = 0.f; }
    __syncthreads();

    int rA = tid >> 4, jA = tid & 15;
    int cB = tid >> 3, jB = tid & 7;

    float acc[TQ];
    #pragma unroll
    for (int r = 0; r < TQ; r++) acc[r] = 0.f;

    for (int dt = 0; dt < NDT; dt++) {
        int d0 = dt * TD;
        for (int idx = tid; idx < CGR * TD; idx += 256) {
            int c = idx / TD, dl = idx % TD;
            int d = d0 + dl;
            float kvK = 0.f, kvV = 0.f;
            if (d < DD) { kvK = kg[c * DD + d]; kvV = vg[c * DD + d]; }
            k_s[c][dl] = kvK;
            v_s[c][dl] = kvV;
        }
        __syncthreads();

        float l0 = 0.f, l1 = 0.f, l2 = 0.f, l3 = 0.f;
        #pragma unroll 8
        for (int c = 0; c < CGR; c++) {
            float qc = q_s[rA][c];
            float4 kv = *(const float4*)&k_s[c][jA * 4];
            l0 += qc * kv.x; l1 += qc * kv.y; l2 += qc * kv.z; l3 += qc * kv.w;
        }
        l0 *= taug; l1 *= taug; l2 *= taug; l3 *= taug;
        int dbase = d0 + jA * 4;
        if (dbase + 0 >= DD) l0 = -1e30f;
        if (dbase + 1 >= DD) l1 = -1e30f;
        if (dbase + 2 >= DD) l2 = -1e30f;
        if (dbase + 3 >= DD) l3 = -1e30f;

        float mx = fmaxf(fmaxf(l0, l1), fmaxf(l2, l3));
        #pragma unroll
        for (int o = 1; o < 16; o <<= 1) mx = fmaxf(mx, __shfl_xor(mx, o));
        float mold = m_s[rA];
        float mnew = fmaxf(mold, mx);
        float e0 = expf(l0 - mnew), e1 = expf(l1 - mnew);
        float e2 = expf(l2 - mnew), e3 = expf(l3 - mnew);
        float rs = e0 + e1 + e2 + e3;
        #pragma unroll
        for (int o = 1; o < 16; o <<= 1) rs += __shfl_xor(rs, o);
        w_s[rA][jA * 4 + 0] = e0;
        w_s[rA][jA * 4 + 1] = e1;
        w_s[rA][jA * 4 + 2] = e2;
        w_s[rA][jA * 4 + 3] = e3;
        if (jA == 0) {
            float scale = expf(mold - mnew);
            s_s[rA] = s_s[rA] * scale + rs;
            m_s[rA] = mnew;
            sc_s[rA] = scale;
        }
        __syncthreads();

        float4 va = *(const float4*)&v_s[cB][jB * 8];
        float4 vb = *(const float4*)&v_s[cB][jB * 8 + 4];
        #pragma unroll
        for (int r = 0; r < TQ; r++) {
            float4 wa = *(const float4*)&w_s[r][jB * 8];
            float4 wb = *(const float4*)&w_s[r][jB * 8 + 4];
            float p = wa.x * va.x + wa.y * va.y + wa.z * va.z + wa.w * va.w
                    + wb.x * vb.x + wb.y * vb.y + wb.z * vb.z + wb.w * vb.w;
            acc[r] = acc[r] * sc_s[r] + p;
        }
        __syncthreads();
    }

    float* ag = a + ((size_t)n * CC + g * CGR + cB) * HWP + q0;
    #pragma unroll
    for (int r = 0; r < TQ; r++) {
        float t = acc[r];
        #pragma unroll
        for (int o = 1; o < 8; o <<= 1) t += __shfl_xor(t, o);
        if (jB == 0) ag[r] = t / s_s[r];
    }
}

// ---------------- gates (i, g, o; f dead since c=0): 1x1 on a + 3x3 on x + LSTM ----
// block: (4-row tile, g, n); thread: (oc, 18-px run); x + a staged in LDS.
__global__ __launch_bounds__(256) void k_gates(const float* __restrict__ x,
                                               const float* __restrict__ a,
                                               const float* __restrict__ Wi_a, const float* __restrict__ Wi_x,
                                               const float* __restrict__ b_i,  const float* __restrict__ g_i,
                                               const float* __restrict__ Wg_a, const float* __restrict__ Wg_x,
                                               const float* __restrict__ b_g,  const float* __restrict__ g_g,
                                               const float* __restrict__ Wo_a, const float* __restrict__ Wo_x,
                                               const float* __restrict__ b_o,  const float* __restrict__ g_o,
                                               float* __restrict__ out) {
    __shared__ float xs[CGR][6][38];
    __shared__ float as_[CGR][144];
    int rt = blockIdx.x, g = blockIdx.y, n = blockIdx.z;
    int y0 = rt * 4, p0 = y0 * WW;
    const float* xg = x + ((size_t)n * CC + g * CGR) * HWP;
    const float* ag = a + ((size_t)n * CC + g * CGR) * HWP;
    for (int idx = threadIdx.x; idx < CGR * 6 * 38; idx += 256) {
        int ci = idx / (6 * 38);
        int rem = idx % (6 * 38);
        int r = rem / 38, c = rem % 38;
        int yy = y0 - 1 + r, cx = c - 1;
        float v = 0.f;
        if ((unsigned)yy < HH && (unsigned)cx < WW) v = xg[ci * HWP + yy * WW + cx];
        (&xs[0][0][0])[idx] = v;
    }
    for (int idx = threadIdx.x; idx < CGR * 144; idx += 256) {
        int c = idx / 144, pp = idx % 144;
        (&as_[0][0])[idx] = ag[c * HWP + p0 + pp];
    }
    __syncthreads();

    int oc = threadIdx.x >> 3;
    int j  = threadIdx.x & 7;
    int rq = j >> 1, cq = (j & 1) * 18;
    int ocg = g * CGR + oc;

    float zi[18], zg[18], zo[18];
    #pragma unroll
    for (int t = 0; t < 18; t++) { zi[t] = 0.f; zg[t] = 0.f; zo[t] = 0.f; }

    // a-term: grouped 1x1
    const float* wia = Wi_a + ocg * CGR;
    const float* wga = Wg_a + ocg * CGR;
    const float* woa = Wo_a + ocg * CGR;
    for (int c = 0; c < CGR; c++) {
        float w1 = wia[c], w2 = wga[c], w3 = woa[c];
        const float* ar = &as_[c][rq * 36 + cq];
        #pragma unroll
        for (int t = 0; t < 18; t++) {
            float av = ar[t];
            zi[t] += w1 * av; zg[t] += w2 * av; zo[t] += w3 * av;
        }
    }

    // x-term: grouped 3x3 SAME
    const float* wix = Wi_x + (size_t)ocg * 576;
    const float* wgx = Wg_x + (size_t)ocg * 576;
    const float* wox = Wo_x + (size_t)ocg * 576;
    for (int ci = 0; ci < CGR; ci++) {
        #pragma unroll
        for (int ky = 0; ky < 3; ky++) {
            const float* xr = &xs[ci][rq + ky][cq];
            #pragma unroll
            for (int kx = 0; kx < 3; kx++) {
                int kidx = ci * 9 + ky * 3 + kx;
                float w1 = wix[kidx], w2 = wgx[kidx], w3 = wox[kidx];
                #pragma unroll
                for (int t = 0; t < 18; t++) {
                    float xv = xr[kx + t];
                    zi[t] += w1 * xv; zg[t] += w2 * xv; zo[t] += w3 * xv;
                }
            }
        }
    }

    float bi = b_i[ocg], gi = g_i[ocg];
    float bg = b_g[ocg], gg = g_g[ocg];
    float bo = b_o[ocg], go = g_o[ocg];
    float* oo = out + ((size_t)n * CC + ocg) * HWP + p0 + rq * 36 + cq;
    #pragma unroll
    for (int t = 0; t < 18; t++) {
        float iv = 1.f / (1.f + expf(-(gi * zi[t] + bi)));
        float gv = tanhf(gg * zg[t] + bg);
        float ov = 1.f / (1.f + expf(-(go * zo[t] + bo)));
        oo[t] = ov * tanhf(iv * gv);
    }
}

extern "C" void kernel_launch(void* const* d_in, const int* in_sizes, int n_in,
                              void* d_out, int out_size, void* d_ws, size_t ws_size,
                              hipStream_t stream) {
    const float* x_in = (const float*)d_in[0];
    // d_in[1] = W_xh (dead: h = 0)
    const float* W_xi = (const float*)d_in[2];
    const float* Wq   = (const float*)d_in[3];
    const float* Wk   = (const float*)d_in[4];
    const float* Wv   = (const float*)d_in[5];
    const float* Wi_a = (const float*)d_in[6];
    const float* Wi_x = (const float*)d_in[7];
    const float* b_i  = (const float*)d_in[8];
    const float* g_i  = (const float*)d_in[9];
    // d_in[10..13] = Wf_a, Wf_x, b_f, g_f (dead: c = 0)
    const float* Wg_a = (const float*)d_in[14];
    const float* Wg_x = (const float*)d_in[15];
    const float* b_g  = (const float*)d_in[16];
    const float* g_g  = (const float*)d_in[17];
    const float* Wo_a = (const float*)d_in[18];
    const float* Wo_x = (const float*)d_in[19];
    const float* b_o  = (const float*)d_in[20];
    const float* g_o  = (const float*)d_in[21];
    const float* tau  = (const float*)d_in[22];
    float* out = (float*)d_out;

    float* ws = (float*)d_ws;
    const size_t sz_x = (size_t)NB * CC * HWP;
    const size_t sz_d = (size_t)NB * CC * DD;
    float* x  = ws;
    float* q  = x + sz_x;
    float* kk = q + sz_x;
    float* vv = kk + sz_d;
    float* aa = vv + sz_d;

    dim3 blk(256);
    k_proj<<<dim3(4, 18, NB), blk, 0, stream>>>(x_in, W_xi, x);
    k_qkv<<<dim3(9, GG, NB), blk, 0, stream>>>(x, Wq, Wk, Wv, q, kk, vv);
    k_attn<<<dim3(HWP / TQ, GG, NB), blk, 0, stream>>>(q, kk, vv, tau, aa);
    k_gates<<<dim3(9, GG, NB), blk, 0, stream>>>(x, aa,
                                                 Wi_a, Wi_x, b_i, g_i,
                                                 Wg_a, Wg_x, b_g, g_g,
                                                 Wo_a, Wo_x, b_o, g_o,
                                                 out);
}

// Round 3
// 352.501 us; speedup vs baseline: 4.3865x; 2.0846x over previous
//
#include <hip/hip_runtime.h>
#include <math.h>

typedef __attribute__((ext_vector_type(8))) short short8;
typedef __attribute__((ext_vector_type(4))) float f32x4;

#define NB   8
#define CIN  128
#define CC   256
#define GG   8
#define CGR  32
#define HH   36
#define WW   36
#define HWP  1296
#define DHH  34
#define DD   1156

#define VBT_STRIDE 1160           // padded v row (16B-aligned rows)
#define VBT_NG     (32 * VBT_STRIDE)

#define TPW  2                    // q-tiles per wave
#define TPB  8                    // tiles per block (4 waves * 2)
#define KS   40                   // k_s row stride (bf16)
#define VS   72                   // v_s row stride (bf16)
#define WSd  72                   // w_s row stride (bf16)

__device__ inline short f2bf(float f) {
    union { float f; unsigned u; } v; v.f = f;
    unsigned r = v.u + 0x7fffu + ((v.u >> 16) & 1u);
    return (short)(r >> 16);
}

// ---------------- 1x1 projection: x = W_xi * x_in ----------------
__global__ __launch_bounds__(256) void k_proj(const float* __restrict__ x_in,
                                              const float* __restrict__ W_xi,
                                              float* __restrict__ x) {
    __shared__ float xs[CIN * 72];
    int chunk = blockIdx.x, rt = blockIdx.y, n = blockIdx.z;
    int p0 = rt * 72;
    const float* xb = x_in + (size_t)n * CIN * HWP + p0;
    for (int idx = threadIdx.x; idx < CIN * 72; idx += 256) {
        int ci = idx / 72, c = idx % 72;
        xs[idx] = xb[ci * HWP + c];
    }
    __syncthreads();
    int oc = chunk * 64 + (threadIdx.x >> 2);
    int j = threadIdx.x & 3;
    const float* w = W_xi + oc * CIN;
    const float* xsj = xs + j * 18;
    float acc[18];
    #pragma unroll
    for (int t = 0; t < 18; t++) acc[t] = 0.f;
    for (int ci = 0; ci < CIN; ci++) {
        float wv = w[ci];
        const float* xr = xsj + ci * 72;
        #pragma unroll
        for (int t = 0; t < 18; t++) acc[t] += wv * xr[t];
    }
    float* xo = x + ((size_t)n * CC + oc) * HWP + p0 + j * 18;
    #pragma unroll
    for (int t = 0; t < 18; t++) xo[t] = acc[t];
}

// ---------------- fused q/k/v grouped 3x3 conv -> bf16 MFMA layouts ----------------
// qb[n][g][p][c] ; kb[n][g][d][c] ; vbt[n][g][c][d(padded 1160)]
__global__ __launch_bounds__(256) void k_qkv(const float* __restrict__ x,
                                             const float* __restrict__ Wq,
                                             const float* __restrict__ Wk,
                                             const float* __restrict__ Wv,
                                             short* __restrict__ qb,
                                             short* __restrict__ kb,
                                             short* __restrict__ vbt) {
    __shared__ float xs[CGR][6][38];
    int rt = blockIdx.x, g = blockIdx.y, n = blockIdx.z;
    int y0 = rt * 4;
    const float* xg = x + ((size_t)n * CC + g * CGR) * HWP;
    for (int idx = threadIdx.x; idx < CGR * 6 * 38; idx += 256) {
        int ci = idx / (6 * 38);
        int rem = idx % (6 * 38);
        int r = rem / 38, c = rem % 38;
        int yy = y0 - 1 + r, cx = c - 1;
        float v = 0.f;
        if ((unsigned)yy < HH && (unsigned)cx < WW) v = xg[ci * HWP + yy * WW + cx];
        (&xs[0][0][0])[idx] = v;
    }
    __syncthreads();

    int oc = threadIdx.x >> 3;
    int j  = threadIdx.x & 7;
    int rq = j >> 1, cq = (j & 1) * 18;
    int ocg = g * CGR + oc;
    const float* wq = Wq + (size_t)ocg * 576;
    const float* wk = Wk + (size_t)ocg * 576;
    const float* wv = Wv + (size_t)ocg * 576;

    float qa[18], ka[18], va[18];
    #pragma unroll
    for (int t = 0; t < 18; t++) { qa[t] = 0.f; ka[t] = 0.f; va[t] = 0.f; }

    for (int ci = 0; ci < CGR; ci++) {
        #pragma unroll
        for (int ky = 0; ky < 3; ky++) {
            const float* xr = &xs[ci][rq + ky][cq];
            #pragma unroll
            for (int kx = 0; kx < 3; kx++) {
                int kidx = ci * 9 + ky * 3 + kx;
                float wqv = wq[kidx], wkv = wk[kidx], wvv = wv[kidx];
                #pragma unroll
                for (int t = 0; t < 18; t++) {
                    float xv = xr[kx + t];
                    qa[t] += wqv * xv;
                    ka[t] += wkv * xv;
                    va[t] += wvv * xv;
                }
            }
        }
    }

    size_t bofs = (size_t)n * GG + g;
    short* qo = qb + bofs * ((size_t)HWP * 32);
    int p = (y0 + rq) * WW + cq;
    #pragma unroll
    for (int t = 0; t < 18; t++) qo[(size_t)(p + t) * 32 + oc] = f2bf(qa[t]);

    int yd = y0 + rq - 1;
    if ((unsigned)yd < DHH) {
        short* ko = kb + bofs * ((size_t)DD * 32) + (size_t)yd * DHH * 32;
        short* vo = vbt + bofs * (size_t)VBT_NG + (size_t)oc * VBT_STRIDE + yd * DHH;
        #pragma unroll
        for (int t = 0; t < 18; t++) {
            int xd = cq + t - 1;
            if ((unsigned)xd < DHH) { ko[(size_t)xd * 32 + oc] = f2bf(ka[t]); vo[xd] = f2bf(va[t]); }
        }
    }
}

// ---------------- MFMA attention, single pass (no max subtraction) ----------------
// out: a_t[n][g][p][c] fp32
__global__ __launch_bounds__(256) void k_attn(const short* __restrict__ qb,
                                              const short* __restrict__ kb,
                                              const short* __restrict__ vbt,
                                              const float* __restrict__ tau,
                                              float* __restrict__ a_t) {
    __shared__ short k_s[64 * KS];
    __shared__ short v_s[32 * VS];
    __shared__ short w_s[4][16 * WSd];

    int qc = blockIdx.x, g = blockIdx.y, n = blockIdx.z;
    int tid = threadIdx.x;
    int wv = tid >> 6, ln = tid & 63;
    int lo = ln & 15, hi = ln >> 4;
    const float taug = tau[g];
    size_t bofs = (size_t)n * GG + g;
    const short* qg = qb + bofs * ((size_t)HWP * 32);
    const short* kg = kb + bofs * ((size_t)DD * 32);
    const short* vg = vbt + bofs * (size_t)VBT_NG;
    float* ag = a_t + bofs * ((size_t)HWP * 32);

    int t0 = qc * TPB + wv * TPW;
    bool tv[TPW];
    short8 qf[TPW];
    #pragma unroll
    for (int t = 0; t < TPW; t++) {
        int tile = t0 + t;
        tv[t] = (tile < 81);
        if (tv[t]) qf[t] = *(const short8*)(qg + (size_t)(tile * 16 + lo) * 32 + hi * 8);
    }

    f32x4 oacc[TPW][2];
    float rs[TPW][4];
    #pragma unroll
    for (int t = 0; t < TPW; t++) {
        #pragma unroll
        for (int cs = 0; cs < 2; cs++) oacc[t][cs] = (f32x4){0.f, 0.f, 0.f, 0.f};
        #pragma unroll
        for (int r = 0; r < 4; r++) rs[t][r] = 0.f;
    }
    const f32x4 fz = {0.f, 0.f, 0.f, 0.f};

    for (int dt = 0; dt < 19; dt++) {
        int d0 = dt << 6;
        {   // stage K tile [d][c]
            int d = tid >> 2, co = (tid & 3) << 3;
            uint4 val = {0u, 0u, 0u, 0u};
            if (d0 + d < DD) val = *(const uint4*)(kg + (size_t)(d0 + d) * 32 + co);
            *(uint4*)(&k_s[d * KS + co]) = val;
        }
        {   // stage V tile [c][d] (straight copy from vbt)
            int c = tid >> 3, dof = (tid & 7) << 3;
            uint4 val = {0u, 0u, 0u, 0u};
            if (d0 + dof + 7 < DD) {
                val = *(const uint4*)(vg + (size_t)c * VBT_STRIDE + d0 + dof);
            } else {
                short tmp[8];
                #pragma unroll
                for (int jj = 0; jj < 8; jj++)
                    tmp[jj] = (d0 + dof + jj < DD) ? vg[(size_t)c * VBT_STRIDE + d0 + dof + jj] : (short)0;
                val = *(uint4*)tmp;
            }
            *(uint4*)(&v_s[c * VS + dof]) = val;
        }
        __syncthreads();

        #pragma unroll
        for (int t = 0; t < TPW; t++) {
            if (tv[t]) {
                // ---- QK^T: S[16q][64d], K=32 channels in one MFMA each ----
                f32x4 s[4];
                #pragma unroll
                for (int sub = 0; sub < 4; sub++) {
                    short8 kf = *(const short8*)(&k_s[(sub * 16 + lo) * KS + hi * 8]);
                    s[sub] = __builtin_amdgcn_mfma_f32_16x16x32_bf16(qf[t], kf, fz, 0, 0, 0);
                }
                // ---- w = exp(tau*s), masked; accumulate row sums; park bf16 W in LDS ----
                #pragma unroll
                for (int sub = 0; sub < 4; sub++) {
                    int dl = d0 + sub * 16 + lo;
                    bool ok = (dl < DD);
                    #pragma unroll
                    for (int r = 0; r < 4; r++) {
                        float w = __expf(taug * s[sub][r]);
                        w = ok ? w : 0.f;
                        rs[t][r] += w;
                        w_s[wv][(hi * 4 + r) * WSd + sub * 16 + lo] = f2bf(w);
                    }
                }
                // ---- PV: O[16q][32c] += W[16q][64d] * Vt[64d][32c] ----
                #pragma unroll
                for (int h = 0; h < 2; h++) {
                    short8 af = *(const short8*)(&w_s[wv][lo * WSd + h * 32 + hi * 8]);
                    #pragma unroll
                    for (int cs = 0; cs < 2; cs++) {
                        short8 vf = *(const short8*)(&v_s[(cs * 16 + lo) * VS + h * 32 + hi * 8]);
                        oacc[t][cs] = __builtin_amdgcn_mfma_f32_16x16x32_bf16(af, vf, oacc[t][cs], 0, 0, 0);
                    }
                }
            }
        }
        __syncthreads();
    }

    // ---- normalize and store (position-major a_t) ----
    #pragma unroll
    for (int t = 0; t < TPW; t++) {
        if (tv[t]) {
            #pragma unroll
            for (int r = 0; r < 4; r++) {
                float sum = rs[t][r];
                sum += __shfl_xor(sum, 1);
                sum += __shfl_xor(sum, 2);
                sum += __shfl_xor(sum, 4);
                sum += __shfl_xor(sum, 8);
                float inv = 1.f / sum;
                int row = (t0 + t) * 16 + hi * 4 + r;
                #pragma unroll
                for (int cs = 0; cs < 2; cs++)
                    ag[(size_t)row * 32 + cs * 16 + lo] = oacc[t][cs][r] * inv;
            }
        }
    }
}

// ---------------- gates (i, g, o; f dead): 1x1 on a + 3x3 on x + LSTM ----------------
__global__ __launch_bounds__(256) void k_gates(const float* __restrict__ x,
                                               const float* __restrict__ a_t,
                                               const float* __restrict__ Wi_a, const float* __restrict__ Wi_x,
                                               const float* __restrict__ b_i,  const float* __restrict__ g_i,
                                               const float* __restrict__ Wg_a, const float* __restrict__ Wg_x,
                                               const float* __restrict__ b_g,  const float* __restrict__ g_g,
                                               const float* __restrict__ Wo_a, const float* __restrict__ Wo_x,
                                               const float* __restrict__ b_o,  const float* __restrict__ g_o,
                                               float* __restrict__ out) {
    __shared__ float xs[CGR][6][38];
    __shared__ float as2[144 * 36];   // [pix][c], stride 36 (16B-aligned rows)
    int rt = blockIdx.x, g = blockIdx.y, n = blockIdx.z;
    int y0 = rt * 4, p0 = y0 * WW;
    const float* xg = x + ((size_t)n * CC + g * CGR) * HWP;
    const float* agb = a_t + (((size_t)n * GG + g) * HWP + p0) * 32;
    for (int idx = threadIdx.x; idx < CGR * 6 * 38; idx += 256) {
        int ci = idx / (6 * 38);
        int rem = idx % (6 * 38);
        int r = rem / 38, c = rem % 38;
        int yy = y0 - 1 + r, cx = c - 1;
        float v = 0.f;
        if ((unsigned)yy < HH && (unsigned)cx < WW) v = xg[ci * HWP + yy * WW + cx];
        (&xs[0][0][0])[idx] = v;
    }
    for (int i4 = threadIdx.x; i4 < 1152; i4 += 256) {
        float4 f4 = *(const float4*)(agb + (size_t)i4 * 4);
        int pp = i4 >> 3, c = (i4 & 7) << 2;
        *(float4*)(&as2[pp * 36 + c]) = f4;
    }
    __syncthreads();

    int oc = threadIdx.x >> 3;
    int j  = threadIdx.x & 7;
    int rq = j >> 1, cq = (j & 1) * 18;
    int ocg = g * CGR + oc;

    float zi[18], zg[18], zo[18];
    #pragma unroll
    for (int t = 0; t < 18; t++) { zi[t] = 0.f; zg[t] = 0.f; zo[t] = 0.f; }

    const float* wia = Wi_a + ocg * CGR;
    const float* wga = Wg_a + ocg * CGR;
    const float* woa = Wo_a + ocg * CGR;
    const float* arow = &as2[(rq * 36 + cq) * 36];
    for (int c = 0; c < CGR; c++) {
        float w1 = wia[c], w2 = wga[c], w3 = woa[c];
        #pragma unroll
        for (int t = 0; t < 18; t++) {
            float av = arow[t * 36 + c];
            zi[t] += w1 * av; zg[t] += w2 * av; zo[t] += w3 * av;
        }
    }

    const float* wix = Wi_x + (size_t)ocg * 576;
    const float* wgx = Wg_x + (size_t)ocg * 576;
    const float* wox = Wo_x + (size_t)ocg * 576;
    for (int ci = 0; ci < CGR; ci++) {
        #pragma unroll
        for (int ky = 0; ky < 3; ky++) {
            const float* xr = &xs[ci][rq + ky][cq];
            #pragma unroll
            for (int kx = 0; kx < 3; kx++) {
                int kidx = ci * 9 + ky * 3 + kx;
                float w1 = wix[kidx], w2 = wgx[kidx], w3 = wox[kidx];
                #pragma unroll
                for (int t = 0; t < 18; t++) {
                    float xv = xr[kx + t];
                    zi[t] += w1 * xv; zg[t] += w2 * xv; zo[t] += w3 * xv;
                }
            }
        }
    }

    float bi = b_i[ocg], gi = g_i[ocg];
    float bg = b_g[ocg], gg = g_g[ocg];
    float bo = b_o[ocg], go = g_o[ocg];
    float* oo = out + ((size_t)n * CC + ocg) * HWP + p0 + rq * 36 + cq;
    #pragma unroll
    for (int t = 0; t < 18; t++) {
        float iv = 1.f / (1.f + expf(-(gi * zi[t] + bi)));
        float gv = tanhf(gg * zg[t] + bg);
        float ov = 1.f / (1.f + expf(-(go * zo[t] + bo)));
        oo[t] = ov * tanhf(iv * gv);
    }
}

extern "C" void kernel_launch(void* const* d_in, const int* in_sizes, int n_in,
                              void* d_out, int out_size, void* d_ws, size_t ws_size,
                              hipStream_t stream) {
    const float* x_in = (const float*)d_in[0];
    const float* W_xi = (const float*)d_in[2];
    const float* Wq   = (const float*)d_in[3];
    const float* Wk   = (const float*)d_in[4];
    const float* Wv   = (const float*)d_in[5];
    const float* Wi_a = (const float*)d_in[6];
    const float* Wi_x = (const float*)d_in[7];
    const float* b_i  = (const float*)d_in[8];
    const float* g_i  = (const float*)d_in[9];
    const float* Wg_a = (const float*)d_in[14];
    const float* Wg_x = (const float*)d_in[15];
    const float* b_g  = (const float*)d_in[16];
    const float* g_g  = (const float*)d_in[17];
    const float* Wo_a = (const float*)d_in[18];
    const float* Wo_x = (const float*)d_in[19];
    const float* b_o  = (const float*)d_in[20];
    const float* g_o  = (const float*)d_in[21];
    const float* tau  = (const float*)d_in[22];
    float* out = (float*)d_out;

    char* ws = (char*)d_ws;
    const size_t x_bytes   = (size_t)NB * CC * HWP * 4;          // 10,616,832
    const size_t at_bytes  = (size_t)NB * GG * HWP * 32 * 4;     // 10,616,832
    const size_t qb_bytes  = (size_t)NB * GG * HWP * 32 * 2;     //  5,308,416
    const size_t kb_bytes  = (size_t)NB * GG * DD * 32 * 2;      //  4,734,976
    float* x   = (float*)ws;                      ws += x_bytes;
    float* a_t = (float*)ws;                      ws += at_bytes;
    short* qbv = (short*)ws;                      ws += qb_bytes;
    short* kbv = (short*)ws;                      ws += kb_bytes;
    short* vbt = (short*)ws;

    dim3 blk(256);
    k_proj<<<dim3(4, 18, NB), blk, 0, stream>>>(x_in, W_xi, x);
    k_qkv<<<dim3(9, GG, NB), blk, 0, stream>>>(x, Wq, Wk, Wv, qbv, kbv, vbt);
    k_attn<<<dim3(11, GG, NB), blk, 0, stream>>>(qbv, kbv, vbt, tau, a_t);
    k_gates<<<dim3(9, GG, NB), blk, 0, stream>>>(x, a_t,
                                                 Wi_a, Wi_x, b_i, g_i,
                                                 Wg_a, Wg_x, b_g, g_g,
                                                 Wo_a, Wo_x, b_o, g_o,
                                                 out);
}

// Round 4
// 242.337 us; speedup vs baseline: 6.3806x; 1.4546x over previous
//
#include <hip/hip_runtime.h>
#include <math.h>

typedef __attribute__((ext_vector_type(8))) short short8;
typedef __attribute__((ext_vector_type(4))) float f32x4;

#define NB   8
#define CIN  128
#define CC   256
#define GG   8
#define CGR  32
#define HH   36
#define WW   36
#define HWP  1296
#define DHH  34
#define DD   1156

#define PPW  38                   // padded width
#define PPN  1444                 // 38*38

#define VBT_STRIDE 1160
#define VBT_NG     (32 * VBT_STRIDE)

#define TPW  2
#define TPB  8
#define KS   40
#define VS   72
#define WSd  72

__device__ inline short f2bf(float f) {
    union { float f; unsigned u; } v; v.f = f;
    unsigned r = v.u + 0x7fffu + ((v.u >> 16) & 1u);
    return (short)(r >> 16);
}

// ---------------- weight pack: Wq/Wk/Wv -> wpk[conv*8+g][tap][oc][ci^swz] bf16 ----------------
__global__ __launch_bounds__(256) void k_pack(const float* __restrict__ Wq,
                                              const float* __restrict__ Wk,
                                              const float* __restrict__ Wv,
                                              short* __restrict__ wpk) {
    int idx = blockIdx.x * 256 + threadIdx.x;
    if (idx >= 3 * 8 * 9 * 32 * 32) return;
    int cpos = idx & 31;
    int oc   = (idx >> 5) & 31;
    int tap  = (idx >> 10) % 9;
    int cg   = idx / 9216;            // conv*8+g
    int conv = cg >> 3, g = cg & 7;
    int ci = cpos ^ ((oc & 3) << 3);  // involutive swizzle
    const float* W = (conv == 0) ? Wq : (conv == 1) ? Wk : Wv;
    wpk[idx] = f2bf(W[(size_t)(g * 32 + oc) * 576 + ci * 9 + tap]);
}

// ---------------- 1x1 projection: x = W_xi * x_in (fp32 + bf16-padded copies) ----------------
__global__ __launch_bounds__(256) void k_proj(const float* __restrict__ x_in,
                                              const float* __restrict__ W_xi,
                                              float* __restrict__ x,
                                              short* __restrict__ xpb) {
    __shared__ float xs[CIN * 72];
    int chunk = blockIdx.x, rt = blockIdx.y, n = blockIdx.z;
    int p0 = rt * 72;
    const float* xb = x_in + (size_t)n * CIN * HWP + p0;
    for (int idx = threadIdx.x; idx < CIN * 72; idx += 256) {
        int ci = idx / 72, c = idx % 72;
        xs[idx] = xb[ci * HWP + c];
    }
    __syncthreads();
    int oc = chunk * 64 + (threadIdx.x >> 2);
    int j = threadIdx.x & 3;
    const float* w = W_xi + oc * CIN;
    const float* xsj = xs + j * 18;
    float acc[18];
    #pragma unroll
    for (int t = 0; t < 18; t++) acc[t] = 0.f;
    for (int ci = 0; ci < CIN; ci++) {
        float wv = w[ci];
        const float* xr = xsj + ci * 72;
        #pragma unroll
        for (int t = 0; t < 18; t++) acc[t] += wv * xr[t];
    }
    float* xo = x + ((size_t)n * CC + oc) * HWP + p0 + j * 18;
    #pragma unroll
    for (int t = 0; t < 18; t++) xo[t] = acc[t];

    // bf16 zero-padded pixel-major copy for MFMA convs
    int g = oc >> 5, c = oc & 31;
    int y = 2 * rt + (j >> 1), x0 = (j & 1) * 18;
    short* xpw = xpb + ((size_t)(n * GG + g) * PPN + (size_t)(y + 1) * PPW + x0 + 1) * 32 + c;
    #pragma unroll
    for (int t = 0; t < 18; t++) xpw[t * 32] = f2bf(acc[t]);
}

// ---------------- MFMA grouped 3x3 conv for q/k/v ----------------
// blockIdx: x=chunk(0..6), y=conv*8+g, z=n. Each wave: 3 pixel-tiles of 16.
__global__ __launch_bounds__(256) void k_qkvM(const short* __restrict__ xpb,
                                              const short* __restrict__ wpk,
                                              short* __restrict__ qb,
                                              short* __restrict__ kb,
                                              short* __restrict__ vbt) {
    __shared__ short w_lds[9 * 32 * 32];
    int chunk = blockIdx.x, cg = blockIdx.y, n = blockIdx.z;
    int conv = cg >> 3, g = cg & 7;

    const short* wsrc = wpk + (size_t)cg * 9216;
    for (int idx = threadIdx.x; idx < 1152; idx += 256)
        *(uint4*)(&w_lds[idx * 8]) = *(const uint4*)(wsrc + idx * 8);
    __syncthreads();

    int tid = threadIdx.x;
    int wv = tid >> 6, ln = tid & 63, lo = ln & 15, hi = ln >> 4;
    const short* xg = xpb + (size_t)(n * GG + g) * PPN * 32;
    int swz = (hi * 8) ^ ((lo & 3) << 3);

    f32x4 acc[3][2];
    #pragma unroll
    for (int tt = 0; tt < 3; tt++)
        #pragma unroll
        for (int ot = 0; ot < 2; ot++) acc[tt][ot] = (f32x4){0.f, 0.f, 0.f, 0.f};

    int tbase = chunk * 12 + wv * 3;
    #pragma unroll
    for (int tt = 0; tt < 3; tt++) {
        int tile = tbase + tt;
        if (tile < 81) {
            int p = tile * 16 + lo;
            int y = p / 36, xx = p - y * 36;
            const short* ab = xg + ((size_t)((y + 1) * PPW + xx + 1) * 32 + hi * 8);
            #pragma unroll
            for (int tap = 0; tap < 9; tap++) {
                int toff = (tap / 3 - 1) * PPW + (tap % 3 - 1);
                short8 af = *(const short8*)(ab + toff * 32);
                short8 b0 = *(const short8*)(&w_lds[tap * 1024 + lo * 32 + swz]);
                short8 b1 = *(const short8*)(&w_lds[tap * 1024 + (16 + lo) * 32 + swz]);
                acc[tt][0] = __builtin_amdgcn_mfma_f32_16x16x32_bf16(af, b0, acc[tt][0], 0, 0, 0);
                acc[tt][1] = __builtin_amdgcn_mfma_f32_16x16x32_bf16(af, b1, acc[tt][1], 0, 0, 0);
            }
        }
    }

    size_t bofs = (size_t)n * GG + g;
    #pragma unroll
    for (int tt = 0; tt < 3; tt++) {
        int tile = tbase + tt;
        if (tile < 81) {
            #pragma unroll
            for (int r = 0; r < 4; r++) {
                int p = tile * 16 + hi * 4 + r;
                int y = p / 36, xx = p - y * 36;
                #pragma unroll
                for (int ot = 0; ot < 2; ot++) {
                    short val = f2bf(acc[tt][ot][r]);
                    int oc = ot * 16 + lo;
                    if (conv == 0) {
                        qb[bofs * ((size_t)HWP * 32) + (size_t)p * 32 + oc] = val;
                    } else if ((unsigned)(y - 1) < DHH && (unsigned)(xx - 1) < DHH) {
                        int d = (y - 1) * DHH + (xx - 1);
                        if (conv == 1) kb[bofs * ((size_t)DD * 32) + (size_t)d * 32 + oc] = val;
                        else           vbt[bofs * (size_t)VBT_NG + (size_t)oc * VBT_STRIDE + d] = val;
                    }
                }
            }
        }
    }
}

// ---------------- MFMA attention, single pass (no max subtraction) ----------------
__global__ __launch_bounds__(256) void k_attn(const short* __restrict__ qb,
                                              const short* __restrict__ kb,
                                              const short* __restrict__ vbt,
                                              const float* __restrict__ tau,
                                              float* __restrict__ a_t) {
    __shared__ short k_s[64 * KS];
    __shared__ short v_s[32 * VS];
    __shared__ short w_s[4][16 * WSd];

    int qc = blockIdx.x, g = blockIdx.y, n = blockIdx.z;
    int tid = threadIdx.x;
    int wv = tid >> 6, ln = tid & 63;
    int lo = ln & 15, hi = ln >> 4;
    const float taug = tau[g];
    size_t bofs = (size_t)n * GG + g;
    const short* qg = qb + bofs * ((size_t)HWP * 32);
    const short* kg = kb + bofs * ((size_t)DD * 32);
    const short* vg = vbt + bofs * (size_t)VBT_NG;
    float* ag = a_t + bofs * ((size_t)HWP * 32);

    int t0 = qc * TPB + wv * TPW;
    bool tv[TPW];
    short8 qf[TPW];
    #pragma unroll
    for (int t = 0; t < TPW; t++) {
        int tile = t0 + t;
        tv[t] = (tile < 81);
        if (tv[t]) qf[t] = *(const short8*)(qg + (size_t)(tile * 16 + lo) * 32 + hi * 8);
    }

    f32x4 oacc[TPW][2];
    float rs[TPW][4];
    #pragma unroll
    for (int t = 0; t < TPW; t++) {
        #pragma unroll
        for (int cs = 0; cs < 2; cs++) oacc[t][cs] = (f32x4){0.f, 0.f, 0.f, 0.f};
        #pragma unroll
        for (int r = 0; r < 4; r++) rs[t][r] = 0.f;
    }
    const f32x4 fz = {0.f, 0.f, 0.f, 0.f};

    for (int dt = 0; dt < 19; dt++) {
        int d0 = dt << 6;
        {
            int d = tid >> 2, co = (tid & 3) << 3;
            uint4 val = {0u, 0u, 0u, 0u};
            if (d0 + d < DD) val = *(const uint4*)(kg + (size_t)(d0 + d) * 32 + co);
            *(uint4*)(&k_s[d * KS + co]) = val;
        }
        {
            int c = tid >> 3, dof = (tid & 7) << 3;
            uint4 val = {0u, 0u, 0u, 0u};
            if (d0 + dof + 7 < DD) {
                val = *(const uint4*)(vg + (size_t)c * VBT_STRIDE + d0 + dof);
            } else {
                short tmp[8];
                #pragma unroll
                for (int jj = 0; jj < 8; jj++)
                    tmp[jj] = (d0 + dof + jj < DD) ? vg[(size_t)c * VBT_STRIDE + d0 + dof + jj] : (short)0;
                val = *(uint4*)tmp;
            }
            *(uint4*)(&v_s[c * VS + dof]) = val;
        }
        __syncthreads();

        #pragma unroll
        for (int t = 0; t < TPW; t++) {
            if (tv[t]) {
                f32x4 s[4];
                #pragma unroll
                for (int sub = 0; sub < 4; sub++) {
                    short8 kf = *(const short8*)(&k_s[(sub * 16 + lo) * KS + hi * 8]);
                    s[sub] = __builtin_amdgcn_mfma_f32_16x16x32_bf16(qf[t], kf, fz, 0, 0, 0);
                }
                #pragma unroll
                for (int sub = 0; sub < 4; sub++) {
                    int dl = d0 + sub * 16 + lo;
                    bool ok = (dl < DD);
                    #pragma unroll
                    for (int r = 0; r < 4; r++) {
                        float w = __expf(taug * s[sub][r]);
                        w = ok ? w : 0.f;
                        rs[t][r] += w;
                        w_s[wv][(hi * 4 + r) * WSd + sub * 16 + lo] = f2bf(w);
                    }
                }
                #pragma unroll
                for (int h = 0; h < 2; h++) {
                    short8 af = *(const short8*)(&w_s[wv][lo * WSd + h * 32 + hi * 8]);
                    #pragma unroll
                    for (int cs = 0; cs < 2; cs++) {
                        short8 vf = *(const short8*)(&v_s[(cs * 16 + lo) * VS + h * 32 + hi * 8]);
                        oacc[t][cs] = __builtin_amdgcn_mfma_f32_16x16x32_bf16(af, vf, oacc[t][cs], 0, 0, 0);
                    }
                }
            }
        }
        __syncthreads();
    }

    #pragma unroll
    for (int t = 0; t < TPW; t++) {
        if (tv[t]) {
            #pragma unroll
            for (int r = 0; r < 4; r++) {
                float sum = rs[t][r];
                sum += __shfl_xor(sum, 1);
                sum += __shfl_xor(sum, 2);
                sum += __shfl_xor(sum, 4);
                sum += __shfl_xor(sum, 8);
                float inv = 1.f / sum;
                int row = (t0 + t) * 16 + hi * 4 + r;
                #pragma unroll
                for (int cs = 0; cs < 2; cs++)
                    ag[(size_t)row * 32 + cs * 16 + lo] = oacc[t][cs][r] * inv;
            }
        }
    }
}

// ---------------- gates (i, g, o; f dead): 1x1 on a + 3x3 on x + LSTM ----------------
__global__ __launch_bounds__(256) void k_gates(const float* __restrict__ x,
                                               const float* __restrict__ a_t,
                                               const float* __restrict__ Wi_a, const float* __restrict__ Wi_x,
                                               const float* __restrict__ b_i,  const float* __restrict__ g_i,
                                               const float* __restrict__ Wg_a, const float* __restrict__ Wg_x,
                                               const float* __restrict__ b_g,  const float* __restrict__ g_g,
                                               const float* __restrict__ Wo_a, const float* __restrict__ Wo_x,
                                               const float* __restrict__ b_o,  const float* __restrict__ g_o,
                                               float* __restrict__ out) {
    __shared__ float xs[CGR][6][38];
    __shared__ float as2[144 * 36];
    int rt = blockIdx.x, g = blockIdx.y, n = blockIdx.z;
    int y0 = rt * 4, p0 = y0 * WW;
    const float* xg = x + ((size_t)n * CC + g * CGR) * HWP;
    const float* agb = a_t + (((size_t)n * GG + g) * HWP + p0) * 32;
    for (int idx = threadIdx.x; idx < CGR * 6 * 38; idx += 256) {
        int ci = idx / (6 * 38);
        int rem = idx % (6 * 38);
        int r = rem / 38, c = rem % 38;
        int yy = y0 - 1 + r, cx = c - 1;
        float v = 0.f;
        if ((unsigned)yy < HH && (unsigned)cx < WW) v = xg[ci * HWP + yy * WW + cx];
        (&xs[0][0][0])[idx] = v;
    }
    for (int i4 = threadIdx.x; i4 < 1152; i4 += 256) {
        float4 f4 = *(const float4*)(agb + (size_t)i4 * 4);
        int pp = i4 >> 3, c = (i4 & 7) << 2;
        *(float4*)(&as2[pp * 36 + c]) = f4;
    }
    __syncthreads();

    int oc = threadIdx.x >> 3;
    int j  = threadIdx.x & 7;
    int rq = j >> 1, cq = (j & 1) * 18;
    int ocg = g * CGR + oc;

    float zi[18], zg[18], zo[18];
    #pragma unroll
    for (int t = 0; t < 18; t++) { zi[t] = 0.f; zg[t] = 0.f; zo[t] = 0.f; }

    const float* wia = Wi_a + ocg * CGR;
    const float* wga = Wg_a + ocg * CGR;
    const float* woa = Wo_a + ocg * CGR;
    const float* arow = &as2[(rq * 36 + cq) * 36];
    for (int c = 0; c < CGR; c++) {
        float w1 = wia[c], w2 = wga[c], w3 = woa[c];
        #pragma unroll
        for (int t = 0; t < 18; t++) {
            float av = arow[t * 36 + c];
            zi[t] += w1 * av; zg[t] += w2 * av; zo[t] += w3 * av;
        }
    }

    const float* wix = Wi_x + (size_t)ocg * 576;
    const float* wgx = Wg_x + (size_t)ocg * 576;
    const float* wox = Wo_x + (size_t)ocg * 576;
    for (int ci = 0; ci < CGR; ci++) {
        #pragma unroll
        for (int ky = 0; ky < 3; ky++) {
            const float* xr = &xs[ci][rq + ky][cq];
            #pragma unroll
            for (int kx = 0; kx < 3; kx++) {
                int kidx = ci * 9 + ky * 3 + kx;
                float w1 = wix[kidx], w2 = wgx[kidx], w3 = wox[kidx];
                #pragma unroll
                for (int t = 0; t < 18; t++) {
                    float xv = xr[kx + t];
                    zi[t] += w1 * xv; zg[t] += w2 * xv; zo[t] += w3 * xv;
                }
            }
        }
    }

    float bi = b_i[ocg], gi = g_i[ocg];
    float bg = b_g[ocg], gg = g_g[ocg];
    float bo = b_o[ocg], go = g_o[ocg];
    float* oo = out + ((size_t)n * CC + ocg) * HWP + p0 + rq * 36 + cq;
    #pragma unroll
    for (int t = 0; t < 18; t++) {
        float iv = 1.f / (1.f + expf(-(gi * zi[t] + bi)));
        float gv = tanhf(gg * zg[t] + bg);
        float ov = 1.f / (1.f + expf(-(go * zo[t] + bo)));
        oo[t] = ov * tanhf(iv * gv);
    }
}

extern "C" void kernel_launch(void* const* d_in, const int* in_sizes, int n_in,
                              void* d_out, int out_size, void* d_ws, size_t ws_size,
                              hipStream_t stream) {
    const float* x_in = (const float*)d_in[0];
    const float* W_xi = (const float*)d_in[2];
    const float* Wq   = (const float*)d_in[3];
    const float* Wk   = (const float*)d_in[4];
    const float* Wv   = (const float*)d_in[5];
    const float* Wi_a = (const float*)d_in[6];
    const float* Wi_x = (const float*)d_in[7];
    const float* b_i  = (const float*)d_in[8];
    const float* g_i  = (const float*)d_in[9];
    const float* Wg_a = (const float*)d_in[14];
    const float* Wg_x = (const float*)d_in[15];
    const float* b_g  = (const float*)d_in[16];
    const float* g_g  = (const float*)d_in[17];
    const float* Wo_a = (const float*)d_in[18];
    const float* Wo_x = (const float*)d_in[19];
    const float* b_o  = (const float*)d_in[20];
    const float* g_o  = (const float*)d_in[21];
    const float* tau  = (const float*)d_in[22];
    float* out = (float*)d_out;

    char* ws = (char*)d_ws;
    const size_t x_bytes   = (size_t)NB * CC * HWP * 4;
    const size_t at_bytes  = (size_t)NB * GG * HWP * 32 * 4;
    const size_t qb_bytes  = (size_t)NB * GG * HWP * 32 * 2;
    const size_t kb_bytes  = (size_t)NB * GG * DD * 32 * 2;
    const size_t vbt_bytes = (size_t)NB * GG * VBT_NG * 2;
    const size_t xpb_bytes = (size_t)NB * GG * PPN * 32 * 2;
    float* x   = (float*)ws;                      ws += x_bytes;
    float* a_t = (float*)ws;                      ws += at_bytes;
    short* qbv = (short*)ws;                      ws += qb_bytes;
    short* kbv = (short*)ws;                      ws += kb_bytes;
    short* vbt = (short*)ws;                      ws += vbt_bytes;
    short* xpb = (short*)ws;                      ws += xpb_bytes;
    short* wpk = (short*)ws;

    dim3 blk(256);
    hipMemsetAsync(xpb, 0, xpb_bytes, stream);
    k_pack<<<dim3(864), blk, 0, stream>>>(Wq, Wk, Wv, wpk);
    k_proj<<<dim3(4, 18, NB), blk, 0, stream>>>(x_in, W_xi, x, xpb);
    k_qkvM<<<dim3(7, 24, NB), blk, 0, stream>>>(xpb, wpk, qbv, kbv, vbt);
    k_attn<<<dim3(11, GG, NB), blk, 0, stream>>>(qbv, kbv, vbt, tau, a_t);
    k_gates<<<dim3(9, GG, NB), blk, 0, stream>>>(x, a_t,
                                                 Wi_a, Wi_x, b_i, g_i,
                                                 Wg_a, Wg_x, b_g, g_g,
                                                 Wo_a, Wo_x, b_o, g_o,
                                                 out);
}

// Round 5
// 135.577 us; speedup vs baseline: 11.4050x; 1.7874x over previous
//
#include <hip/hip_runtime.h>
#include <math.h>

typedef __attribute__((ext_vector_type(8))) short short8;
typedef __attribute__((ext_vector_type(4))) float f32x4;

#define NB   8
#define CIN  128
#define CC   256
#define GG   8
#define CGR  32
#define HH   36
#define WW   36
#define HWP  1296
#define DHH  34
#define DD   1156

#define PPW  38
#define PPN  1444

#define VBT_STRIDE 1160
#define VBT_NG     (32 * VBT_STRIDE)

#define TPW  2
#define TPB  8
#define KS   40
#define VS   72
#define WSd  72

__device__ inline short f2bf(float f) {
    union { float f; unsigned u; } v; v.f = f;
    unsigned r = v.u + 0x7fffu + ((v.u >> 16) & 1u);
    return (short)(r >> 16);
}

__device__ inline float sigm(float z) { return 1.f / (1.f + __expf(-z)); }
__device__ inline float tanh_fast(float z) { return 2.f / (1.f + __expf(-2.f * z)) - 1.f; }

// ---------------- weight pack: Wq/Wk/Wv -> wpk[conv*8+g][tap][oc][ci^swz] bf16 ----------------
__global__ __launch_bounds__(256) void k_pack(const float* __restrict__ Wq,
                                              const float* __restrict__ Wk,
                                              const float* __restrict__ Wv,
                                              short* __restrict__ wpk) {
    int idx = blockIdx.x * 256 + threadIdx.x;
    if (idx >= 3 * 8 * 9 * 32 * 32) return;
    int cpos = idx & 31;
    int oc   = (idx >> 5) & 31;
    int tap  = (idx >> 10) % 9;
    int cg   = idx / 9216;
    int conv = cg >> 3, g = cg & 7;
    int ci = cpos ^ ((oc & 3) << 3);
    const float* W = (conv == 0) ? Wq : (conv == 1) ? Wk : Wv;
    wpk[idx] = f2bf(W[(size_t)(g * 32 + oc) * 576 + ci * 9 + tap]);
}

// ---------------- gate weight pack: wgpk[g][gate][tap(0..8=x,9=a)][oc][ci^swz] ----------------
__global__ __launch_bounds__(256) void k_packG(const float* __restrict__ Wi_x, const float* __restrict__ Wi_a,
                                               const float* __restrict__ Wg_x, const float* __restrict__ Wg_a,
                                               const float* __restrict__ Wo_x, const float* __restrict__ Wo_a,
                                               short* __restrict__ wgpk) {
    int idx = blockIdx.x * 256 + threadIdx.x;
    if (idx >= 8 * 3 * 10 * 32 * 32) return;
    int cpos = idx & 31;
    int oc   = (idx >> 5) & 31;
    int tap  = (idx >> 10) % 10;
    int gg_  = idx / 10240;
    int g    = gg_ / 3, gate = gg_ % 3;
    int ci = cpos ^ ((oc & 3) << 3);
    const float* Wx = (gate == 0) ? Wi_x : (gate == 1) ? Wg_x : Wo_x;
    const float* Wa = (gate == 0) ? Wi_a : (gate == 1) ? Wg_a : Wo_a;
    float v = (tap < 9) ? Wx[(size_t)(g * 32 + oc) * 576 + ci * 9 + tap]
                        : Wa[(g * 32 + oc) * 32 + ci];
    wgpk[idx] = f2bf(v);
}

// ---------------- 1x1 projection: xpb = bf16 padded pixel-major (W_xi * x_in) ----------------
__global__ __launch_bounds__(256) void k_proj(const float* __restrict__ x_in,
                                              const float* __restrict__ W_xi,
                                              short* __restrict__ xpb) {
    __shared__ float xs[CIN * 72];
    int chunk = blockIdx.x, rt = blockIdx.y, n = blockIdx.z;
    int p0 = rt * 72;
    const float* xb = x_in + (size_t)n * CIN * HWP + p0;
    for (int idx = threadIdx.x; idx < CIN * 72; idx += 256) {
        int ci = idx / 72, c = idx % 72;
        xs[idx] = xb[ci * HWP + c];
    }
    __syncthreads();
    int oc = chunk * 64 + (threadIdx.x >> 2);
    int j = threadIdx.x & 3;
    const float* w = W_xi + oc * CIN;
    const float* xsj = xs + j * 18;
    float acc[18];
    #pragma unroll
    for (int t = 0; t < 18; t++) acc[t] = 0.f;
    for (int ci = 0; ci < CIN; ci++) {
        float wv = w[ci];
        const float* xr = xsj + ci * 72;
        #pragma unroll
        for (int t = 0; t < 18; t++) acc[t] += wv * xr[t];
    }
    int g = oc >> 5, c = oc & 31;
    int y = 2 * rt + (j >> 1), x0 = (j & 1) * 18;
    short* xpw = xpb + ((size_t)(n * GG + g) * PPN + (size_t)(y + 1) * PPW + x0 + 1) * 32 + c;
    #pragma unroll
    for (int t = 0; t < 18; t++) xpw[t * 32] = f2bf(acc[t]);
}

// ---------------- MFMA grouped 3x3 conv for q/k/v ----------------
__global__ __launch_bounds__(256) void k_qkvM(const short* __restrict__ xpb,
                                              const short* __restrict__ wpk,
                                              short* __restrict__ qb,
                                              short* __restrict__ kb,
                                              short* __restrict__ vbt) {
    __shared__ short w_lds[9 * 32 * 32];
    int chunk = blockIdx.x, cg = blockIdx.y, n = blockIdx.z;
    int conv = cg >> 3, g = cg & 7;

    const short* wsrc = wpk + (size_t)cg * 9216;
    for (int idx = threadIdx.x; idx < 1152; idx += 256)
        *(uint4*)(&w_lds[idx * 8]) = *(const uint4*)(wsrc + idx * 8);
    __syncthreads();

    int tid = threadIdx.x;
    int wv = tid >> 6, ln = tid & 63, lo = ln & 15, hi = ln >> 4;
    const short* xg = xpb + (size_t)(n * GG + g) * PPN * 32;
    int swz = (hi * 8) ^ ((lo & 3) << 3);

    f32x4 acc[3][2];
    #pragma unroll
    for (int tt = 0; tt < 3; tt++)
        #pragma unroll
        for (int ot = 0; ot < 2; ot++) acc[tt][ot] = (f32x4){0.f, 0.f, 0.f, 0.f};

    int tbase = chunk * 12 + wv * 3;
    #pragma unroll
    for (int tt = 0; tt < 3; tt++) {
        int tile = tbase + tt;
        if (tile < 81) {
            int p = tile * 16 + lo;
            int y = p / 36, xx = p - y * 36;
            const short* ab = xg + ((size_t)((y + 1) * PPW + xx + 1) * 32 + hi * 8);
            #pragma unroll
            for (int tap = 0; tap < 9; tap++) {
                int toff = (tap / 3 - 1) * PPW + (tap % 3 - 1);
                short8 af = *(const short8*)(ab + toff * 32);
                short8 b0 = *(const short8*)(&w_lds[tap * 1024 + lo * 32 + swz]);
                short8 b1 = *(const short8*)(&w_lds[tap * 1024 + (16 + lo) * 32 + swz]);
                acc[tt][0] = __builtin_amdgcn_mfma_f32_16x16x32_bf16(af, b0, acc[tt][0], 0, 0, 0);
                acc[tt][1] = __builtin_amdgcn_mfma_f32_16x16x32_bf16(af, b1, acc[tt][1], 0, 0, 0);
            }
        }
    }

    size_t bofs = (size_t)n * GG + g;
    #pragma unroll
    for (int tt = 0; tt < 3; tt++) {
        int tile = tbase + tt;
        if (tile < 81) {
            #pragma unroll
            for (int r = 0; r < 4; r++) {
                int p = tile * 16 + hi * 4 + r;
                int y = p / 36, xx = p - y * 36;
                #pragma unroll
                for (int ot = 0; ot < 2; ot++) {
                    short val = f2bf(acc[tt][ot][r]);
                    int oc = ot * 16 + lo;
                    if (conv == 0) {
                        qb[bofs * ((size_t)HWP * 32) + (size_t)p * 32 + oc] = val;
                    } else if ((unsigned)(y - 1) < DHH && (unsigned)(xx - 1) < DHH) {
                        int d = (y - 1) * DHH + (xx - 1);
                        if (conv == 1) kb[bofs * ((size_t)DD * 32) + (size_t)d * 32 + oc] = val;
                        else           vbt[bofs * (size_t)VBT_NG + (size_t)oc * VBT_STRIDE + d] = val;
                    }
                }
            }
        }
    }
}

// ---------------- MFMA attention, single pass -> bf16 a_b[p][c] ----------------
__global__ __launch_bounds__(256) void k_attn(const short* __restrict__ qb,
                                              const short* __restrict__ kb,
                                              const short* __restrict__ vbt,
                                              const float* __restrict__ tau,
                                              short* __restrict__ a_b) {
    __shared__ short k_s[64 * KS];
    __shared__ short v_s[32 * VS];
    __shared__ short w_s[4][16 * WSd];

    int qc = blockIdx.x, g = blockIdx.y, n = blockIdx.z;
    int tid = threadIdx.x;
    int wv = tid >> 6, ln = tid & 63;
    int lo = ln & 15, hi = ln >> 4;
    const float taug = tau[g];
    size_t bofs = (size_t)n * GG + g;
    const short* qg = qb + bofs * ((size_t)HWP * 32);
    const short* kg = kb + bofs * ((size_t)DD * 32);
    const short* vg = vbt + bofs * (size_t)VBT_NG;
    short* ag = a_b + bofs * ((size_t)HWP * 32);

    int t0 = qc * TPB + wv * TPW;
    bool tv[TPW];
    short8 qf[TPW];
    #pragma unroll
    for (int t = 0; t < TPW; t++) {
        int tile = t0 + t;
        tv[t] = (tile < 81);
        if (tv[t]) qf[t] = *(const short8*)(qg + (size_t)(tile * 16 + lo) * 32 + hi * 8);
    }

    f32x4 oacc[TPW][2];
    float rs[TPW][4];
    #pragma unroll
    for (int t = 0; t < TPW; t++) {
        #pragma unroll
        for (int cs = 0; cs < 2; cs++) oacc[t][cs] = (f32x4){0.f, 0.f, 0.f, 0.f};
        #pragma unroll
        for (int r = 0; r < 4; r++) rs[t][r] = 0.f;
    }
    const f32x4 fz = {0.f, 0.f, 0.f, 0.f};

    for (int dt = 0; dt < 19; dt++) {
        int d0 = dt << 6;
        {
            int d = tid >> 2, co = (tid & 3) << 3;
            uint4 val = {0u, 0u, 0u, 0u};
            if (d0 + d < DD) val = *(const uint4*)(kg + (size_t)(d0 + d) * 32 + co);
            *(uint4*)(&k_s[d * KS + co]) = val;
        }
        {
            int c = tid >> 3, dof = (tid & 7) << 3;
            uint4 val = {0u, 0u, 0u, 0u};
            if (d0 + dof + 7 < DD) {
                val = *(const uint4*)(vg + (size_t)c * VBT_STRIDE + d0 + dof);
            } else {
                short tmp[8];
                #pragma unroll
                for (int jj = 0; jj < 8; jj++)
                    tmp[jj] = (d0 + dof + jj < DD) ? vg[(size_t)c * VBT_STRIDE + d0 + dof + jj] : (short)0;
                val = *(uint4*)tmp;
            }
            *(uint4*)(&v_s[c * VS + dof]) = val;
        }
        __syncthreads();

        #pragma unroll
        for (int t = 0; t < TPW; t++) {
            if (tv[t]) {
                f32x4 s[4];
                #pragma unroll
                for (int sub = 0; sub < 4; sub++) {
                    short8 kf = *(const short8*)(&k_s[(sub * 16 + lo) * KS + hi * 8]);
                    s[sub] = __builtin_amdgcn_mfma_f32_16x16x32_bf16(qf[t], kf, fz, 0, 0, 0);
                }
                #pragma unroll
                for (int sub = 0; sub < 4; sub++) {
                    int dl = d0 + sub * 16 + lo;
                    bool ok = (dl < DD);
                    #pragma unroll
                    for (int r = 0; r < 4; r++) {
                        float w = __expf(taug * s[sub][r]);
                        w = ok ? w : 0.f;
                        rs[t][r] += w;
                        w_s[wv][(hi * 4 + r) * WSd + sub * 16 + lo] = f2bf(w);
                    }
                }
                #pragma unroll
                for (int h = 0; h < 2; h++) {
                    short8 af = *(const short8*)(&w_s[wv][lo * WSd + h * 32 + hi * 8]);
                    #pragma unroll
                    for (int cs = 0; cs < 2; cs++) {
                        short8 vf = *(const short8*)(&v_s[(cs * 16 + lo) * VS + h * 32 + hi * 8]);
                        oacc[t][cs] = __builtin_amdgcn_mfma_f32_16x16x32_bf16(af, vf, oacc[t][cs], 0, 0, 0);
                    }
                }
            }
        }
        __syncthreads();
    }

    #pragma unroll
    for (int t = 0; t < TPW; t++) {
        if (tv[t]) {
            #pragma unroll
            for (int r = 0; r < 4; r++) {
                float sum = rs[t][r];
                sum += __shfl_xor(sum, 1);
                sum += __shfl_xor(sum, 2);
                sum += __shfl_xor(sum, 4);
                sum += __shfl_xor(sum, 8);
                float inv = 1.f / sum;
                int row = (t0 + t) * 16 + hi * 4 + r;
                #pragma unroll
                for (int cs = 0; cs < 2; cs++)
                    ag[(size_t)row * 32 + cs * 16 + lo] = f2bf(oacc[t][cs][r] * inv);
            }
        }
    }
}

// ---------------- MFMA gates: i/g/o (f dead) + fused LSTM epilogue ----------------
// block: (chunk 0..6, g, n); wave: 3 pixel-tiles; 60 KB LDS of packed gate weights.
__global__ __launch_bounds__(256) void k_gatesM(const short* __restrict__ xpb,
                                                const short* __restrict__ a_b,
                                                const short* __restrict__ wgpk,
                                                const float* __restrict__ b_i, const float* __restrict__ g_i,
                                                const float* __restrict__ b_g, const float* __restrict__ g_g,
                                                const float* __restrict__ b_o, const float* __restrict__ g_o,
                                                float* __restrict__ out) {
    __shared__ short w_lds[3 * 10 * 32 * 32];
    int chunk = blockIdx.x, g = blockIdx.y, n = blockIdx.z;

    const short* wsrc = wgpk + (size_t)g * 30720;
    for (int idx = threadIdx.x; idx < 3840; idx += 256)
        *(uint4*)(&w_lds[idx * 8]) = *(const uint4*)(wsrc + idx * 8);
    __syncthreads();

    int tid = threadIdx.x;
    int wv = tid >> 6, ln = tid & 63, lo = ln & 15, hi = ln >> 4;
    const short* xg = xpb + (size_t)(n * GG + g) * PPN * 32;
    const short* ab_a = a_b + (size_t)(n * GG + g) * HWP * 32;
    int swz = (hi * 8) ^ ((lo & 3) << 3);

    f32x4 acc[3][3][2];   // [gate][tile][oc-half]
    #pragma unroll
    for (int gt = 0; gt < 3; gt++)
        #pragma unroll
        for (int tt = 0; tt < 3; tt++)
            #pragma unroll
            for (int ot = 0; ot < 2; ot++) acc[gt][tt][ot] = (f32x4){0.f, 0.f, 0.f, 0.f};

    int tbase = chunk * 12 + wv * 3;
    bool tv[3];
    int pbase[3];
    #pragma unroll
    for (int tt = 0; tt < 3; tt++) {
        int tile = tbase + tt;
        tv[tt] = (tile < 81);
        int p = tile * 16 + lo;
        int y = p / 36, xx = p - y * 36;
        pbase[tt] = ((y + 1) * PPW + xx + 1) * 32 + hi * 8;
    }

    // x-term taps 0..8
    #pragma unroll
    for (int tap = 0; tap < 9; tap++) {
        int toff = (tap / 3 - 1) * PPW + (tap % 3 - 1);
        short8 af[3];
        #pragma unroll
        for (int tt = 0; tt < 3; tt++) {
            af[tt] = (short8){0,0,0,0,0,0,0,0};
            if (tv[tt]) af[tt] = *(const short8*)(xg + pbase[tt] + toff * 32);
        }
        #pragma unroll
        for (int gt = 0; gt < 3; gt++) {
            const short* wl = &w_lds[(gt * 10 + tap) * 1024];
            short8 b0 = *(const short8*)(&wl[lo * 32 + swz]);
            short8 b1 = *(const short8*)(&wl[(16 + lo) * 32 + swz]);
            #pragma unroll
            for (int tt = 0; tt < 3; tt++) {
                acc[gt][tt][0] = __builtin_amdgcn_mfma_f32_16x16x32_bf16(af[tt], b0, acc[gt][tt][0], 0, 0, 0);
                acc[gt][tt][1] = __builtin_amdgcn_mfma_f32_16x16x32_bf16(af[tt], b1, acc[gt][tt][1], 0, 0, 0);
            }
        }
    }
    // a-term (tap 9)
    {
        short8 af[3];
        #pragma unroll
        for (int tt = 0; tt < 3; tt++) {
            af[tt] = (short8){0,0,0,0,0,0,0,0};
            if (tv[tt]) af[tt] = *(const short8*)(ab_a + (size_t)((tbase + tt) * 16 + lo) * 32 + hi * 8);
        }
        #pragma unroll
        for (int gt = 0; gt < 3; gt++) {
            const short* wl = &w_lds[(gt * 10 + 9) * 1024];
            short8 b0 = *(const short8*)(&wl[lo * 32 + swz]);
            short8 b1 = *(const short8*)(&wl[(16 + lo) * 32 + swz]);
            #pragma unroll
            for (int tt = 0; tt < 3; tt++) {
                acc[gt][tt][0] = __builtin_amdgcn_mfma_f32_16x16x32_bf16(af[tt], b0, acc[gt][tt][0], 0, 0, 0);
                acc[gt][tt][1] = __builtin_amdgcn_mfma_f32_16x16x32_bf16(af[tt], b1, acc[gt][tt][1], 0, 0, 0);
            }
        }
    }

    // epilogue: per-lane gains/biases for its two oc's
    int oc0 = g * 32 + lo, oc1 = oc0 + 16;
    float gi0 = g_i[oc0], gi1 = g_i[oc1], bi0 = b_i[oc0], bi1 = b_i[oc1];
    float gg0 = g_g[oc0], gg1 = g_g[oc1], bg0 = b_g[oc0], bg1 = b_g[oc1];
    float go0 = g_o[oc0], go1 = g_o[oc1], bo0 = b_o[oc0], bo1 = b_o[oc1];

    #pragma unroll
    for (int tt = 0; tt < 3; tt++) {
        if (tv[tt]) {
            int tile = tbase + tt;
            #pragma unroll
            for (int r = 0; r < 4; r++) {
                int p = tile * 16 + hi * 4 + r;
                #pragma unroll
                for (int ot = 0; ot < 2; ot++) {
                    float gi = ot ? gi1 : gi0, bi = ot ? bi1 : bi0;
                    float gg_ = ot ? gg1 : gg0, bg = ot ? bg1 : bg0;
                    float go = ot ? go1 : go0, bo = ot ? bo1 : bo0;
                    float iv = sigm(gi * acc[0][tt][ot][r] + bi);
                    float gv = tanh_fast(gg_ * acc[1][tt][ot][r] + bg);
                    float ov = sigm(go * acc[2][tt][ot][r] + bo);
                    int oc = g * 32 + ot * 16 + lo;
                    out[((size_t)n * CC + oc) * HWP + p] = ov * tanh_fast(iv * gv);
                }
            }
        }
    }
}

extern "C" void kernel_launch(void* const* d_in, const int* in_sizes, int n_in,
                              void* d_out, int out_size, void* d_ws, size_t ws_size,
                              hipStream_t stream) {
    const float* x_in = (const float*)d_in[0];
    const float* W_xi = (const float*)d_in[2];
    const float* Wq   = (const float*)d_in[3];
    const float* Wk   = (const float*)d_in[4];
    const float* Wv   = (const float*)d_in[5];
    const float* Wi_a = (const float*)d_in[6];
    const float* Wi_x = (const float*)d_in[7];
    const float* b_i  = (const float*)d_in[8];
    const float* g_i  = (const float*)d_in[9];
    const float* Wg_a = (const float*)d_in[14];
    const float* Wg_x = (const float*)d_in[15];
    const float* b_g  = (const float*)d_in[16];
    const float* g_g  = (const float*)d_in[17];
    const float* Wo_a = (const float*)d_in[18];
    const float* Wo_x = (const float*)d_in[19];
    const float* b_o  = (const float*)d_in[20];
    const float* g_o  = (const float*)d_in[21];
    const float* tau  = (const float*)d_in[22];
    float* out = (float*)d_out;

    char* ws = (char*)d_ws;
    const size_t ab_bytes  = (size_t)NB * GG * HWP * 32 * 2;     // 5,308,416
    const size_t qb_bytes  = (size_t)NB * GG * HWP * 32 * 2;
    const size_t kb_bytes  = (size_t)NB * GG * DD * 32 * 2;
    const size_t vbt_bytes = (size_t)NB * GG * VBT_NG * 2;
    const size_t xpb_bytes = (size_t)NB * GG * PPN * 32 * 2;
    const size_t wpk_bytes = (size_t)3 * 8 * 9 * 32 * 32 * 2;
    short* a_b = (short*)ws;                      ws += ab_bytes;
    short* qbv = (short*)ws;                      ws += qb_bytes;
    short* kbv = (short*)ws;                      ws += kb_bytes;
    short* vbt = (short*)ws;                      ws += vbt_bytes;
    short* xpb = (short*)ws;                      ws += xpb_bytes;
    short* wpk = (short*)ws;                      ws += wpk_bytes;
    short* wgpk = (short*)ws;

    dim3 blk(256);
    hipMemsetAsync(xpb, 0, xpb_bytes, stream);
    k_pack<<<dim3(864), blk, 0, stream>>>(Wq, Wk, Wv, wpk);
    k_packG<<<dim3(960), blk, 0, stream>>>(Wi_x, Wi_a, Wg_x, Wg_a, Wo_x, Wo_a, wgpk);
    k_proj<<<dim3(4, 18, NB), blk, 0, stream>>>(x_in, W_xi, xpb);
    k_qkvM<<<dim3(7, 24, NB), blk, 0, stream>>>(xpb, wpk, qbv, kbv, vbt);
    k_attn<<<dim3(11, GG, NB), blk, 0, stream>>>(qbv, kbv, vbt, tau, a_b);
    k_gatesM<<<dim3(7, GG, NB), blk, 0, stream>>>(xpb, a_b, wgpk,
                                                  b_i, g_i, b_g, g_g, b_o, g_o,
                                                  out);
}

// Round 6
// 117.104 us; speedup vs baseline: 13.2041x; 1.1578x over previous
//
#include <hip/hip_runtime.h>
#include <math.h>

typedef __attribute__((ext_vector_type(8))) short short8;
typedef __attribute__((ext_vector_type(4))) float f32x4;

#define NB   8
#define CIN  128
#define CC   256
#define GG   8
#define CGR  32
#define HH   36
#define WW   36
#define HWP  1296
#define DHH  34
#define DD   1156

#define PPW  38
#define PPN  1444

#define VBT_STRIDE 1160
#define VBT_NG     (32 * VBT_STRIDE)

#define TPW  2
#define TPB  8
#define KS   40
#define VS   72
#define WS2  72

__device__ inline short f2bf(float f) {
    union { float f; unsigned u; } v; v.f = f;
    unsigned r = v.u + 0x7fffu + ((v.u >> 16) & 1u);
    return (short)(r >> 16);
}

__device__ inline float sigm(float z) { return 1.f / (1.f + __expf(-z)); }
__device__ inline float tanh_fast(float z) { return 2.f / (1.f + __expf(-2.f * z)) - 1.f; }

// ---------------- weight pack: Wq/Wk/Wv -> wpk[conv*8+g][tap][oc][ci^swz] bf16 ----------------
// tau folded into Wq (qb is consumed only by attention logits).
__global__ __launch_bounds__(256) void k_pack(const float* __restrict__ Wq,
                                              const float* __restrict__ Wk,
                                              const float* __restrict__ Wv,
                                              const float* __restrict__ tau,
                                              short* __restrict__ wpk) {
    int idx = blockIdx.x * 256 + threadIdx.x;
    if (idx >= 3 * 8 * 9 * 32 * 32) return;
    int cpos = idx & 31;
    int oc   = (idx >> 5) & 31;
    int tap  = (idx >> 10) % 9;
    int cg   = idx / 9216;
    int conv = cg >> 3, g = cg & 7;
    int ci = cpos ^ ((oc & 3) << 3);
    const float* W = (conv == 0) ? Wq : (conv == 1) ? Wk : Wv;
    float v = W[(size_t)(g * 32 + oc) * 576 + ci * 9 + tap];
    if (conv == 0) v *= tau[g];
    wpk[idx] = f2bf(v);
}

// ---------------- gate weight pack: wgpk[g][gate][tap(0..8=x,9=a)][oc][ci^swz] ----------------
__global__ __launch_bounds__(256) void k_packG(const float* __restrict__ Wi_x, const float* __restrict__ Wi_a,
                                               const float* __restrict__ Wg_x, const float* __restrict__ Wg_a,
                                               const float* __restrict__ Wo_x, const float* __restrict__ Wo_a,
                                               short* __restrict__ wgpk) {
    int idx = blockIdx.x * 256 + threadIdx.x;
    if (idx >= 8 * 3 * 10 * 32 * 32) return;
    int cpos = idx & 31;
    int oc   = (idx >> 5) & 31;
    int tap  = (idx >> 10) % 10;
    int gg_  = idx / 10240;
    int g    = gg_ / 3, gate = gg_ % 3;
    int ci = cpos ^ ((oc & 3) << 3);
    const float* Wx = (gate == 0) ? Wi_x : (gate == 1) ? Wg_x : Wo_x;
    const float* Wa = (gate == 0) ? Wi_a : (gate == 1) ? Wg_a : Wo_a;
    float v = (tap < 9) ? Wx[(size_t)(g * 32 + oc) * 576 + ci * 9 + tap]
                        : Wa[(g * 32 + oc) * 32 + ci];
    wgpk[idx] = f2bf(v);
}

// ---------------- 1x1 projection: xpb = bf16 padded pixel-major (W_xi * x_in) ----------------
__global__ __launch_bounds__(256) void k_proj(const float* __restrict__ x_in,
                                              const float* __restrict__ W_xi,
                                              short* __restrict__ xpb) {
    __shared__ float xs[CIN * 72];
    int chunk = blockIdx.x, rt = blockIdx.y, n = blockIdx.z;
    int p0 = rt * 72;
    const float* xb = x_in + (size_t)n * CIN * HWP + p0;
    for (int idx = threadIdx.x; idx < CIN * 72; idx += 256) {
        int ci = idx / 72, c = idx % 72;
        xs[idx] = xb[ci * HWP + c];
    }
    __syncthreads();
    int oc = chunk * 64 + (threadIdx.x >> 2);
    int j = threadIdx.x & 3;
    const float* w = W_xi + oc * CIN;
    const float* xsj = xs + j * 18;
    float acc[18];
    #pragma unroll
    for (int t = 0; t < 18; t++) acc[t] = 0.f;
    for (int ci = 0; ci < CIN; ci++) {
        float wv = w[ci];
        const float* xr = xsj + ci * 72;
        #pragma unroll
        for (int t = 0; t < 18; t++) acc[t] += wv * xr[t];
    }
    int g = oc >> 5, c = oc & 31;
    int y = 2 * rt + (j >> 1), x0 = (j & 1) * 18;
    short* xpw = xpb + ((size_t)(n * GG + g) * PPN + (size_t)(y + 1) * PPW + x0 + 1) * 32 + c;
    #pragma unroll
    for (int t = 0; t < 18; t++) xpw[t * 32] = f2bf(acc[t]);
}

// ---------------- MFMA grouped 3x3 conv for q/k/v ----------------
// grid: (x = n*8+g, y = chunk, z = conv) -> all blocks sharing one (n,g) land on the
// same XCD (linear id mod 8 == g), so xpb is fetched once per XCD-L2.
__global__ __launch_bounds__(256) void k_qkvM(const short* __restrict__ xpb,
                                              const short* __restrict__ wpk,
                                              short* __restrict__ qb,
                                              short* __restrict__ kb,
                                              short* __restrict__ vbt) {
    __shared__ short w_lds[9 * 32 * 32];
    int ng = blockIdx.x, chunk = blockIdx.y, conv = blockIdx.z;
    int n = ng >> 3, g = ng & 7;

    const short* wsrc = wpk + (size_t)(conv * 8 + g) * 9216;
    for (int idx = threadIdx.x; idx < 1152; idx += 256)
        *(uint4*)(&w_lds[idx * 8]) = *(const uint4*)(wsrc + idx * 8);
    __syncthreads();

    int tid = threadIdx.x;
    int wv = tid >> 6, ln = tid & 63, lo = ln & 15, hi = ln >> 4;
    const short* xg = xpb + (size_t)(n * GG + g) * PPN * 32;
    int swz = (hi * 8) ^ ((lo & 3) << 3);

    f32x4 acc[3][2];
    #pragma unroll
    for (int tt = 0; tt < 3; tt++)
        #pragma unroll
        for (int ot = 0; ot < 2; ot++) acc[tt][ot] = (f32x4){0.f, 0.f, 0.f, 0.f};

    int tbase = chunk * 12 + wv * 3;
    #pragma unroll
    for (int tt = 0; tt < 3; tt++) {
        int tile = tbase + tt;
        if (tile < 81) {
            int p = tile * 16 + lo;
            int y = p / 36, xx = p - y * 36;
            const short* ab = xg + ((size_t)((y + 1) * PPW + xx + 1) * 32 + hi * 8);
            #pragma unroll
            for (int tap = 0; tap < 9; tap++) {
                int toff = (tap / 3 - 1) * PPW + (tap % 3 - 1);
                short8 af = *(const short8*)(ab + toff * 32);
                short8 b0 = *(const short8*)(&w_lds[tap * 1024 + lo * 32 + swz]);
                short8 b1 = *(const short8*)(&w_lds[tap * 1024 + (16 + lo) * 32 + swz]);
                acc[tt][0] = __builtin_amdgcn_mfma_f32_16x16x32_bf16(af, b0, acc[tt][0], 0, 0, 0);
                acc[tt][1] = __builtin_amdgcn_mfma_f32_16x16x32_bf16(af, b1, acc[tt][1], 0, 0, 0);
            }
        }
    }

    size_t bofs = (size_t)n * GG + g;
    #pragma unroll
    for (int tt = 0; tt < 3; tt++) {
        int tile = tbase + tt;
        if (tile < 81) {
            #pragma unroll
            for (int r = 0; r < 4; r++) {
                int p = tile * 16 + hi * 4 + r;
                int y = p / 36, xx = p - y * 36;
                #pragma unroll
                for (int ot = 0; ot < 2; ot++) {
                    short val = f2bf(acc[tt][ot][r]);
                    int oc = ot * 16 + lo;
                    if (conv == 0) {
                        qb[bofs * ((size_t)HWP * 32) + (size_t)p * 32 + oc] = val;
                    } else if ((unsigned)(y - 1) < DHH && (unsigned)(xx - 1) < DHH) {
                        int d = (y - 1) * DHH + (xx - 1);
                        if (conv == 1) kb[bofs * ((size_t)DD * 32) + (size_t)d * 32 + oc] = val;
                        else           vbt[bofs * (size_t)VBT_NG + (size_t)oc * VBT_STRIDE + d] = val;
                    }
                }
            }
        }
    }
}

// ---------------- MFMA attention, single pass, swapped-QK softmax ----------------
// tau pre-folded into q. Pad d's contribute exp(0)=1 to row sums (K,V zero-padded):
// corrected by subtracting the pad count (19*64 - 1156 = 60).
__global__ __launch_bounds__(256) void k_attn(const short* __restrict__ qb,
                                              const short* __restrict__ kb,
                                              const short* __restrict__ vbt,
                                              short* __restrict__ a_b) {
    __shared__ short k_s[64 * KS];
    __shared__ short v_s[32 * VS];
    __shared__ short w_s[4][2][16 * WS2];

    int ng = blockIdx.x, qc = blockIdx.y;    // qc in y: same (n,g) -> same XCD
    int tid = threadIdx.x;
    int wv = tid >> 6, ln = tid & 63;
    int lo = ln & 15, hi = ln >> 4;
    size_t bofs = (size_t)ng;
    const short* qg = qb + bofs * ((size_t)HWP * 32);
    const short* kg = kb + bofs * ((size_t)DD * 32);
    const short* vg = vbt + bofs * (size_t)VBT_NG;
    short* ag = a_b + bofs * ((size_t)HWP * 32);

    int t0 = qc * TPB + wv * TPW;
    bool tv[TPW];
    short8 qf[TPW];
    #pragma unroll
    for (int t = 0; t < TPW; t++) {
        int tile = t0 + t;
        tv[t] = (tile < 81);
        if (tv[t]) qf[t] = *(const short8*)(qg + (size_t)(tile * 16 + lo) * 32 + hi * 8);
    }

    f32x4 oacc[TPW][2];
    float rs[TPW];
    #pragma unroll
    for (int t = 0; t < TPW; t++) {
        #pragma unroll
        for (int cs = 0; cs < 2; cs++) oacc[t][cs] = (f32x4){0.f, 0.f, 0.f, 0.f};
        rs[t] = 0.f;
    }
    const f32x4 fz = {0.f, 0.f, 0.f, 0.f};

    for (int dt = 0; dt < 19; dt++) {
        int d0 = dt << 6;
        {   // stage K tile [d][c], zero-padded
            int d = tid >> 2, co = (tid & 3) << 3;
            uint4 val = {0u, 0u, 0u, 0u};
            if (d0 + d < DD) val = *(const uint4*)(kg + (size_t)(d0 + d) * 32 + co);
            *(uint4*)(&k_s[d * KS + co]) = val;
        }
        {   // stage V tile [c][d], zero-padded
            int c = tid >> 3, dof = (tid & 7) << 3;
            uint4 val = {0u, 0u, 0u, 0u};
            if (d0 + dof + 7 < DD) {
                val = *(const uint4*)(vg + (size_t)c * VBT_STRIDE + d0 + dof);
            } else {
                short tmp[8];
                #pragma unroll
                for (int jj = 0; jj < 8; jj++)
                    tmp[jj] = (d0 + dof + jj < DD) ? vg[(size_t)c * VBT_STRIDE + d0 + dof + jj] : (short)0;
                val = *(uint4*)tmp;
            }
            *(uint4*)(&v_s[c * VS + dof]) = val;
        }
        __syncthreads();

        // hoisted fragments (shared across both q-tiles)
        short8 kf[4];
        #pragma unroll
        for (int sub = 0; sub < 4; sub++)
            kf[sub] = *(const short8*)(&k_s[(sub * 16 + lo) * KS + hi * 8]);
        short8 vf[2][2];
        #pragma unroll
        for (int h = 0; h < 2; h++)
            #pragma unroll
            for (int cs = 0; cs < 2; cs++)
                vf[h][cs] = *(const short8*)(&v_s[(cs * 16 + lo) * VS + h * 32 + hi * 8]);

        #pragma unroll
        for (int t = 0; t < TPW; t++) {
            if (tv[t]) {
                // swapped QK: lane holds 4 consecutive d (sub*16 + hi*4 + r) of q-row lo
                #pragma unroll
                for (int sub = 0; sub < 4; sub++) {
                    f32x4 s2 = __builtin_amdgcn_mfma_f32_16x16x32_bf16(kf[sub], qf[t], fz, 0, 0, 0);
                    float w0 = __expf(s2[0]), w1 = __expf(s2[1]);
                    float w2 = __expf(s2[2]), w3 = __expf(s2[3]);
                    rs[t] += (w0 + w1) + (w2 + w3);
                    unsigned p01, p23;
                    asm("v_cvt_pk_bf16_f32 %0, %1, %2" : "=v"(p01) : "v"(w0), "v"(w1));
                    asm("v_cvt_pk_bf16_f32 %0, %1, %2" : "=v"(p23) : "v"(w2), "v"(w3));
                    uint2 pk; pk.x = p01; pk.y = p23;
                    *(uint2*)(&w_s[wv][t][lo * WS2 + sub * 16 + hi * 4]) = pk;
                }
            }
        }

        #pragma unroll
        for (int t = 0; t < TPW; t++) {
            if (tv[t]) {
                #pragma unroll
                for (int h = 0; h < 2; h++) {
                    short8 af = *(const short8*)(&w_s[wv][t][lo * WS2 + h * 32 + hi * 8]);
                    #pragma unroll
                    for (int cs = 0; cs < 2; cs++)
                        oacc[t][cs] = __builtin_amdgcn_mfma_f32_16x16x32_bf16(af, vf[h][cs], oacc[t][cs], 0, 0, 0);
                }
            }
        }
        __syncthreads();
    }

    // row sums: lane (lo,hi) holds partial for q-row lo; reduce over hi groups,
    // subtract the 60 pad contributions, invert.
    float inv[TPW];
    #pragma unroll
    for (int t = 0; t < TPW; t++) {
        float s = rs[t];
        s += __shfl_xor(s, 16);
        s += __shfl_xor(s, 32);
        inv[t] = 1.f / (s - 60.f);
    }

    #pragma unroll
    for (int t = 0; t < TPW; t++) {
        if (tv[t]) {
            #pragma unroll
            for (int r = 0; r < 4; r++) {
                float iv = __shfl(inv[t], hi * 4 + r);   // q-row hi*4+r lives at lane (hi*4+r)
                int row = (t0 + t) * 16 + hi * 4 + r;
                #pragma unroll
                for (int cs = 0; cs < 2; cs++)
                    ag[(size_t)row * 32 + cs * 16 + lo] = f2bf(oacc[t][cs][r] * iv);
            }
        }
    }
}

// ---------------- MFMA gates: i/g/o (f dead) + fused LSTM epilogue ----------------
// grid: (x = n*8+g, y = chunk) -> same (n,g) on same XCD.
__global__ __launch_bounds__(256) void k_gatesM(const short* __restrict__ xpb,
                                                const short* __restrict__ a_b,
                                                const short* __restrict__ wgpk,
                                                const float* __restrict__ b_i, const float* __restrict__ g_i,
                                                const float* __restrict__ b_g, const float* __restrict__ g_g,
                                                const float* __restrict__ b_o, const float* __restrict__ g_o,
                                                float* __restrict__ out) {
    __shared__ short w_lds[3 * 10 * 32 * 32];
    int ng = blockIdx.x, chunk = blockIdx.y;
    int n = ng >> 3, g = ng & 7;

    const short* wsrc = wgpk + (size_t)g * 30720;
    for (int idx = threadIdx.x; idx < 3840; idx += 256)
        *(uint4*)(&w_lds[idx * 8]) = *(const uint4*)(wsrc + idx * 8);
    __syncthreads();

    int tid = threadIdx.x;
    int wv = tid >> 6, ln = tid & 63, lo = ln & 15, hi = ln >> 4;
    const short* xg = xpb + (size_t)(n * GG + g) * PPN * 32;
    const short* ab_a = a_b + (size_t)(n * GG + g) * HWP * 32;
    int swz = (hi * 8) ^ ((lo & 3) << 3);

    f32x4 acc[3][3][2];
    #pragma unroll
    for (int gt = 0; gt < 3; gt++)
        #pragma unroll
        for (int tt = 0; tt < 3; tt++)
            #pragma unroll
            for (int ot = 0; ot < 2; ot++) acc[gt][tt][ot] = (f32x4){0.f, 0.f, 0.f, 0.f};

    int tbase = chunk * 12 + wv * 3;
    bool tv[3];
    int pbase[3];
    #pragma unroll
    for (int tt = 0; tt < 3; tt++) {
        int tile = tbase + tt;
        tv[tt] = (tile < 81);
        int p = tile * 16 + lo;
        int y = p / 36, xx = p - y * 36;
        pbase[tt] = ((y + 1) * PPW + xx + 1) * 32 + hi * 8;
    }

    #pragma unroll
    for (int tap = 0; tap < 9; tap++) {
        int toff = (tap / 3 - 1) * PPW + (tap % 3 - 1);
        short8 af[3];
        #pragma unroll
        for (int tt = 0; tt < 3; tt++) {
            af[tt] = (short8){0,0,0,0,0,0,0,0};
            if (tv[tt]) af[tt] = *(const short8*)(xg + pbase[tt] + toff * 32);
        }
        #pragma unroll
        for (int gt = 0; gt < 3; gt++) {
            const short* wl = &w_lds[(gt * 10 + tap) * 1024];
            short8 b0 = *(const short8*)(&wl[lo * 32 + swz]);
            short8 b1 = *(const short8*)(&wl[(16 + lo) * 32 + swz]);
            #pragma unroll
            for (int tt = 0; tt < 3; tt++) {
                acc[gt][tt][0] = __builtin_amdgcn_mfma_f32_16x16x32_bf16(af[tt], b0, acc[gt][tt][0], 0, 0, 0);
                acc[gt][tt][1] = __builtin_amdgcn_mfma_f32_16x16x32_bf16(af[tt], b1, acc[gt][tt][1], 0, 0, 0);
            }
        }
    }
    {
        short8 af[3];
        #pragma unroll
        for (int tt = 0; tt < 3; tt++) {
            af[tt] = (short8){0,0,0,0,0,0,0,0};
            if (tv[tt]) af[tt] = *(const short8*)(ab_a + (size_t)((tbase + tt) * 16 + lo) * 32 + hi * 8);
        }
        #pragma unroll
        for (int gt = 0; gt < 3; gt++) {
            const short* wl = &w_lds[(gt * 10 + 9) * 1024];
            short8 b0 = *(const short8*)(&wl[lo * 32 + swz]);
            short8 b1 = *(const short8*)(&wl[(16 + lo) * 32 + swz]);
            #pragma unroll
            for (int tt = 0; tt < 3; tt++) {
                acc[gt][tt][0] = __builtin_amdgcn_mfma_f32_16x16x32_bf16(af[tt], b0, acc[gt][tt][0], 0, 0, 0);
                acc[gt][tt][1] = __builtin_amdgcn_mfma_f32_16x16x32_bf16(af[tt], b1, acc[gt][tt][1], 0, 0, 0);
            }
        }
    }

    int oc0 = g * 32 + lo, oc1 = oc0 + 16;
    float gi0 = g_i[oc0], gi1 = g_i[oc1], bi0 = b_i[oc0], bi1 = b_i[oc1];
    float gg0 = g_g[oc0], gg1 = g_g[oc1], bg0 = b_g[oc0], bg1 = b_g[oc1];
    float go0 = g_o[oc0], go1 = g_o[oc1], bo0 = b_o[oc0], bo1 = b_o[oc1];

    #pragma unroll
    for (int tt = 0; tt < 3; tt++) {
        if (tv[tt]) {
            int tile = tbase + tt;
            #pragma unroll
            for (int r = 0; r < 4; r++) {
                int p = tile * 16 + hi * 4 + r;
                #pragma unroll
                for (int ot = 0; ot < 2; ot++) {
                    float gi = ot ? gi1 : gi0, bi = ot ? bi1 : bi0;
                    float gg_ = ot ? gg1 : gg0, bg = ot ? bg1 : bg0;
                    float go = ot ? go1 : go0, bo = ot ? bo1 : bo0;
                    float iv = sigm(gi * acc[0][tt][ot][r] + bi);
                    float gv = tanh_fast(gg_ * acc[1][tt][ot][r] + bg);
                    float ov = sigm(go * acc[2][tt][ot][r] + bo);
                    int oc = g * 32 + ot * 16 + lo;
                    out[((size_t)n * CC + oc) * HWP + p] = ov * tanh_fast(iv * gv);
                }
            }
        }
    }
}

extern "C" void kernel_launch(void* const* d_in, const int* in_sizes, int n_in,
                              void* d_out, int out_size, void* d_ws, size_t ws_size,
                              hipStream_t stream) {
    const float* x_in = (const float*)d_in[0];
    const float* W_xi = (const float*)d_in[2];
    const float* Wq   = (const float*)d_in[3];
    const float* Wk   = (const float*)d_in[4];
    const float* Wv   = (const float*)d_in[5];
    const float* Wi_a = (const float*)d_in[6];
    const float* Wi_x = (const float*)d_in[7];
    const float* b_i  = (const float*)d_in[8];
    const float* g_i  = (const float*)d_in[9];
    const float* Wg_a = (const float*)d_in[14];
    const float* Wg_x = (const float*)d_in[15];
    const float* b_g  = (const float*)d_in[16];
    const float* g_g  = (const float*)d_in[17];
    const float* Wo_a = (const float*)d_in[18];
    const float* Wo_x = (const float*)d_in[19];
    const float* b_o  = (const float*)d_in[20];
    const float* g_o  = (const float*)d_in[21];
    const float* tau  = (const float*)d_in[22];
    float* out = (float*)d_out;

    char* ws = (char*)d_ws;
    const size_t ab_bytes  = (size_t)NB * GG * HWP * 32 * 2;
    const size_t qb_bytes  = (size_t)NB * GG * HWP * 32 * 2;
    const size_t kb_bytes  = (size_t)NB * GG * DD * 32 * 2;
    const size_t vbt_bytes = (size_t)NB * GG * VBT_NG * 2;
    const size_t xpb_bytes = (size_t)NB * GG * PPN * 32 * 2;
    const size_t wpk_bytes = (size_t)3 * 8 * 9 * 32 * 32 * 2;
    short* a_b = (short*)ws;                      ws += ab_bytes;
    short* qbv = (short*)ws;                      ws += qb_bytes;
    short* kbv = (short*)ws;                      ws += kb_bytes;
    short* vbt = (short*)ws;                      ws += vbt_bytes;
    short* xpb = (short*)ws;                      ws += xpb_bytes;
    short* wpk = (short*)ws;                      ws += wpk_bytes;
    short* wgpk = (short*)ws;

    dim3 blk(256);
    hipMemsetAsync(xpb, 0, xpb_bytes, stream);
    k_pack<<<dim3(864), blk, 0, stream>>>(Wq, Wk, Wv, tau, wpk);
    k_packG<<<dim3(960), blk, 0, stream>>>(Wi_x, Wi_a, Wg_x, Wg_a, Wo_x, Wo_a, wgpk);
    k_proj<<<dim3(4, 18, NB), blk, 0, stream>>>(x_in, W_xi, xpb);
    k_qkvM<<<dim3(64, 7, 3), blk, 0, stream>>>(xpb, wpk, qbv, kbv, vbt);
    k_attn<<<dim3(64, 11), blk, 0, stream>>>(qbv, kbv, vbt, a_b);
    k_gatesM<<<dim3(64, 7), blk, 0, stream>>>(xpb, a_b, wgpk,
                                              b_i, g_i, b_g, g_g, b_o, g_o,
                                              out);
}